// Round 4
// baseline (362.761 us; speedup 1.0000x reference)
//
#include <hip/hip_runtime.h>
#include <hip/hip_bf16.h>
#include <math.h>

#define D_MODEL 512
#define D_INNER 1024
#define D_STATE 128
#define CONV_DIM (D_INNER + 2*D_STATE)        // 1280
#define D_IN_PROJ (2*D_INNER + 2*D_STATE + 1) // 2305
#define NPROJ 2304                            // z + xBC cols (dt col via GEMV)
#define BATCH 8
#define SEQ 2048
#define NROWS (BATCH*SEQ)                     // 16384
#define CHUNK 128
#define NCHUNK (NROWS/CHUNK)                  // 128 total (16 per batch)
#define CPB (SEQ/CHUNK)                       // 16 chunks per batch
#define EPS_RMS 1e-5f

typedef __hip_bfloat16 bf16;
typedef __attribute__((ext_vector_type(8))) short short8;
typedef __attribute__((ext_vector_type(4))) float f32x4;

__device__ __forceinline__ float fbf(bf16 v) { return __bfloat162float(v); }
__device__ __forceinline__ bf16 tbf(float v) { return __float2bfloat16(v); }

// async global->LDS, 16B per lane; LDS dest is wave-uniform base + lane*16
__device__ __forceinline__ void gl2lds16(const bf16* g, bf16* l) {
    __builtin_amdgcn_global_load_lds(
        (const __attribute__((address_space(1))) unsigned int*)g,
        (__attribute__((address_space(3))) unsigned int*)l, 16, 0, 0);
}

// ---------- transpose + convert: dst[r][c] = bf16(src[c*sstride + r]) ----------
__global__ void k_transpose_cvt(const float* __restrict__ src, bf16* __restrict__ dst,
                                int R, int C, int sstride) {
    __shared__ float tile[32][33];
    int c0 = blockIdx.x * 32, r0 = blockIdx.y * 32;
    int tx = threadIdx.x, ty = threadIdx.y;
    #pragma unroll
    for (int i = 0; i < 32; i += 8)
        tile[ty + i][tx] = src[(size_t)(c0 + ty + i) * sstride + (r0 + tx)];
    __syncthreads();
    #pragma unroll
    for (int i = 0; i < 32; i += 8)
        dst[(size_t)(r0 + ty + i) * C + (c0 + tx)] = tbf(tile[tx][ty + i]);
}

// ---------- fused x->bf16 convert + dt GEMV + softplus ----------
__global__ __launch_bounds__(256) void k_dtcvt(
    const float* __restrict__ x, const float* __restrict__ W_in,
    const float* __restrict__ dt_bias,
    bf16* __restrict__ xb, float* __restrict__ dts)
{
    __shared__ float wcol[D_MODEL];
    int tid = threadIdx.x;
    wcol[tid]       = W_in[(size_t)tid * D_IN_PROJ + 2304];
    wcol[tid + 256] = W_in[(size_t)(tid + 256) * D_IN_PROJ + 2304];
    __syncthreads();
    int row  = blockIdx.x * 4 + (tid >> 6);
    int lane = tid & 63;
    const float* xr = x + (size_t)row * D_MODEL;
    float4 a = *(const float4*)(xr + lane * 8);
    float4 b = *(const float4*)(xr + lane * 8 + 4);
    union { bf16 o[8]; uint4 u; } pk;
    pk.o[0]=tbf(a.x); pk.o[1]=tbf(a.y); pk.o[2]=tbf(a.z); pk.o[3]=tbf(a.w);
    pk.o[4]=tbf(b.x); pk.o[5]=tbf(b.y); pk.o[6]=tbf(b.z); pk.o[7]=tbf(b.w);
    *(uint4*)(xb + (size_t)row * D_MODEL + lane * 8) = pk.u;
    const float* wc = wcol + lane * 8;
    float s = a.x*wc[0]+a.y*wc[1]+a.z*wc[2]+a.w*wc[3]
            + b.x*wc[4]+b.y*wc[5]+b.z*wc[6]+b.w*wc[7];
    #pragma unroll
    for (int off = 32; off; off >>= 1) s += __shfl_xor(s, off);
    if (lane == 0) {
        float raw = s + dt_bias[0];
        dts[row] = raw > 20.f ? raw : log1pf(expf(raw));
    }
}

// ---------- batched NT GEMM, 128x128 tile, BK=64, global_load_lds staging ----------
// MODE 0: fp32 out.  MODE 1: bf16 out.  MODE 2: Sm-fused bf16 out (mask*decay*dt + D diag).
template<int MODE>
__global__ __launch_bounds__(256) void k_bgemm(
    const bf16* __restrict__ A, int lda, size_t sA,
    const bf16* __restrict__ Bt, int ldb, size_t sB,
    void* __restrict__ Cv, int ldc, size_t sC, int K,
    const float* __restrict__ svec, const float* __restrict__ dts,
    const float* __restrict__ Dp)
{
    constexpr int BK = 64;
    __shared__ __align__(16) bf16 As[128][BK];
    __shared__ __align__(16) bf16 Bs[128][BK];
    const int tid = threadIdx.x, lane = tid & 63, wave = tid >> 6;
    const int wm = (wave & 1) * 64, wn = (wave >> 1) * 64;
    const int lr = lane & 15, quad = lane >> 4;
    const size_t bm = (size_t)blockIdx.x * 128;
    const size_t bn = (size_t)blockIdx.y * 128;
    const size_t bi = blockIdx.z;
    A  += bi * sA;
    Bt += bi * sB;
    const int srow = (lane >> 3);        // row within 8-row group
    const int scol = (lane & 7) * 8;     // 16B column group

    f32x4 acc[4][4];
    #pragma unroll
    for (int i = 0; i < 4; ++i)
        #pragma unroll
        for (int j = 0; j < 4; ++j) acc[i][j] = (f32x4){0.f,0.f,0.f,0.f};

    for (int k0 = 0; k0 < K; k0 += BK) {
        __syncthreads();
        #pragma unroll
        for (int q = 0; q < 4; ++q) {
            int rg = wave * 32 + q * 8;
            gl2lds16(A  + (bm + rg + srow) * lda + k0 + scol, &As[rg][0]);
            gl2lds16(Bt + (bn + rg + srow) * ldb + k0 + scol, &Bs[rg][0]);
        }
        __syncthreads();
        #pragma unroll
        for (int ks = 0; ks < BK; ks += 32) {
            short8 af[4], bg[4];
            #pragma unroll
            for (int i = 0; i < 4; ++i)
                af[i] = *(const short8*)(&As[wm + i*16 + lr][ks + quad*8]);
            #pragma unroll
            for (int j = 0; j < 4; ++j)
                bg[j] = *(const short8*)(&Bs[wn + j*16 + lr][ks + quad*8]);
            #pragma unroll
            for (int i = 0; i < 4; ++i)
                #pragma unroll
                for (int j = 0; j < 4; ++j)
                    acc[i][j] = __builtin_amdgcn_mfma_f32_16x16x32_bf16(af[i], bg[j], acc[i][j], 0,0,0);
        }
    }
    const int rb = (int)bi * CHUNK;
    #pragma unroll
    for (int i = 0; i < 4; ++i)
        #pragma unroll
        for (int j = 0; j < 4; ++j)
            #pragma unroll
            for (int r = 0; r < 4; ++r) {
                size_t row = bm + wm + i*16 + quad*4 + r;
                size_t col = bn + wn + j*16 + lr;
                float v = acc[i][j][r];
                if (MODE == 0) {
                    ((float*)Cv + bi*sC)[row * ldc + col] = v;
                } else if (MODE == 1) {
                    ((bf16*)Cv + bi*sC)[row * ldc + col] = tbf(v);
                } else {
                    float o = 0.f;
                    if (col <= row) {
                        o = v * expf(svec[rb + row] - svec[rb + col]) * dts[rb + col];
                        if (col == row) o += Dp[0];
                    }
                    ((bf16*)Cv + bi*sC)[row * ldc + col] = tbf(o);
                }
            }
}

// ---------- GEMM1 with split output: cols<1024 -> zb, else xBCin ----------
__global__ __launch_bounds__(256) void k_gemm_in(
    const bf16* __restrict__ A, const bf16* __restrict__ Bt,
    bf16* __restrict__ zb, bf16* __restrict__ xBCin, int K)
{
    constexpr int BK = 64;
    __shared__ __align__(16) bf16 As[128][BK];
    __shared__ __align__(16) bf16 Bs[128][BK];
    const int tid = threadIdx.x, lane = tid & 63, wave = tid >> 6;
    const int wm = (wave & 1) * 64, wn = (wave >> 1) * 64;
    const int lr = lane & 15, quad = lane >> 4;
    const size_t bm = (size_t)blockIdx.x * 128;
    const int bn = blockIdx.y * 128;
    const int srow = (lane >> 3);
    const int scol = (lane & 7) * 8;

    f32x4 acc[4][4];
    #pragma unroll
    for (int i = 0; i < 4; ++i)
        #pragma unroll
        for (int j = 0; j < 4; ++j) acc[i][j] = (f32x4){0.f,0.f,0.f,0.f};

    for (int k0 = 0; k0 < K; k0 += BK) {
        __syncthreads();
        #pragma unroll
        for (int q = 0; q < 4; ++q) {
            int rg = wave * 32 + q * 8;
            gl2lds16(A  + (bm + rg + srow) * K + k0 + scol, &As[rg][0]);
            gl2lds16(Bt + ((size_t)bn + rg + srow) * K + k0 + scol, &Bs[rg][0]);
        }
        __syncthreads();
        #pragma unroll
        for (int ks = 0; ks < BK; ks += 32) {
            short8 af[4], bg[4];
            #pragma unroll
            for (int i = 0; i < 4; ++i)
                af[i] = *(const short8*)(&As[wm + i*16 + lr][ks + quad*8]);
            #pragma unroll
            for (int j = 0; j < 4; ++j)
                bg[j] = *(const short8*)(&Bs[wn + j*16 + lr][ks + quad*8]);
            #pragma unroll
            for (int i = 0; i < 4; ++i)
                #pragma unroll
                for (int j = 0; j < 4; ++j)
                    acc[i][j] = __builtin_amdgcn_mfma_f32_16x16x32_bf16(af[i], bg[j], acc[i][j], 0,0,0);
        }
    }
    #pragma unroll
    for (int i = 0; i < 4; ++i)
        #pragma unroll
        for (int j = 0; j < 4; ++j)
            #pragma unroll
            for (int r = 0; r < 4; ++r) {
                size_t row = bm + wm + i*16 + quad*4 + r;
                int col = bn + wn + j*16 + lr;
                float v = acc[i][j][r];
                if (col < D_INNER) zb[row * D_INNER + col] = tbf(v);
                else xBCin[row * CONV_DIM + (col - D_INNER)] = tbf(v);
            }
}

// ---------- per-chunk cumsum of a_t = A*dt, decay factors ----------
__global__ void k_prep(const float* __restrict__ dts, const float* __restrict__ A_log,
                       float* __restrict__ svec, float* __restrict__ wvec,
                       float* __restrict__ esvec, float* __restrict__ Pc)
{
    int chunk = blockIdx.x, t = threadIdx.x;  // 128 threads
    int row = chunk * CHUNK + t;
    float A = -expf(A_log[0]);
    __shared__ float sh[CHUNK];
    sh[t] = A * dts[row];
    __syncthreads();
    for (int off = 1; off < CHUNK; off <<= 1) {
        float v = (t >= off) ? sh[t - off] : 0.f;
        __syncthreads();
        sh[t] += v;
        __syncthreads();
    }
    float s = sh[t], sL = sh[CHUNK - 1];
    svec[row]  = s;
    wvec[row]  = expf(sL - s) * dts[row];
    esvec[row] = expf(s);
    if (t == CHUNK - 1) Pc[chunk] = expf(sL);
}

// ---------- conv+silu for x-region, writes Xt directly into B2[:, 0:128] ----------
__global__ __launch_bounds__(256) void k_conv_x(
    const bf16* __restrict__ xBCin, const float* __restrict__ conv_w,
    const float* __restrict__ conv_b, bf16* __restrict__ B2)
{
    __shared__ __align__(16) bf16 Ls[131][128];
    const int chunk = blockIdx.y;
    const int p0 = blockIdx.x * 128;
    const int tid = threadIdx.x;
    const bool first = (chunk % CPB) == 0;
    const size_t rowbase = (size_t)chunk * CHUNK;
    for (int i = tid; i < 131 * 16; i += 256) {
        int r = i >> 4, cg = (i & 15) << 3;
        uint4 v = (uint4){0,0,0,0};
        if (!(first && r < 3))
            v = *(const uint4*)(xBCin + (rowbase + r - 3) * CONV_DIM + p0 + cg);
        *(uint4*)(&Ls[r][cg]) = v;
    }
    __syncthreads();
    const int p = tid & 127;
    const int half = tid >> 7;
    const int ch = p0 + p;
    float4 w = *(const float4*)(conv_w + ch * 4);
    float bias = conv_b[ch];
    bf16* outrow = B2 + (size_t)chunk * (D_INNER * 256) + (size_t)ch * 256;
    float xv[11];
    #pragma unroll
    for (int i = 0; i < 3; ++i) xv[i + 8] = fbf(Ls[half * 64 + i][p]);
    for (int v = 0; v < 8; ++v) {
        int t0 = half * 64 + v * 8;
        xv[0]=xv[8]; xv[1]=xv[9]; xv[2]=xv[10];
        #pragma unroll
        for (int i = 3; i < 11; ++i) xv[i] = fbf(Ls[t0 + i][p]);
        union { bf16 o[8]; uint4 u; } pk;
        #pragma unroll
        for (int j = 0; j < 8; ++j) {
            float a = bias + w.x*xv[j] + w.y*xv[j+1] + w.z*xv[j+2] + w.w*xv[j+3];
            pk.o[j] = tbf(a / (1.f + expf(-a)));
        }
        *(uint4*)(outrow + t0) = pk.u;
    }
}

// ---------- conv+silu for B/C region: raw B, raw C, scaled Bw^T, scaled Cs ----------
__global__ __launch_bounds__(256) void k_conv_bc(
    const bf16* __restrict__ xBCin, const float* __restrict__ conv_w,
    const float* __restrict__ conv_b, const float* __restrict__ wvec,
    const float* __restrict__ esvec,
    bf16* __restrict__ Braw, bf16* __restrict__ Craw,
    bf16* __restrict__ Bw, bf16* __restrict__ A2)
{
    __shared__ __align__(16) bf16 Ls[131][256];
    const int chunk = blockIdx.x;
    const bool first = (chunk % CPB) == 0;
    const size_t rowbase = (size_t)chunk * CHUNK;
    for (int i = threadIdx.x; i < 131 * 32; i += 256) {
        int r = i >> 5, cg = (i & 31) << 3;
        uint4 v = (uint4){0,0,0,0};
        if (!(first && r < 3))
            v = *(const uint4*)(xBCin + (rowbase + r - 3) * CONV_DIM + D_INNER + cg);
        *(uint4*)(&Ls[r][cg]) = v;
    }
    __syncthreads();
    const int n   = threadIdx.x & 127;
    const int reg = threadIdx.x >> 7;  // 0 = B, 1 = C
    const int cl  = reg * 128 + n;
    const int ch  = D_INNER + cl;
    float4 w = *(const float4*)(conv_w + ch * 4);
    float bias = conv_b[ch];
    float xv[11];
    #pragma unroll
    for (int i = 0; i < 3; ++i) xv[i + 8] = fbf(Ls[i][cl]);
    for (int v = 0; v < 16; ++v) {
        int t0 = v * 8;
        xv[0]=xv[8]; xv[1]=xv[9]; xv[2]=xv[10];
        #pragma unroll
        for (int i = 3; i < 11; ++i) xv[i] = fbf(Ls[t0 + i][cl]);
        float o[8];
        #pragma unroll
        for (int j = 0; j < 8; ++j) {
            float a = bias + w.x*xv[j] + w.y*xv[j+1] + w.z*xv[j+2] + w.w*xv[j+3];
            o[j] = a / (1.f + expf(-a));
        }
        if (reg == 0) {
            union { bf16 ob[8]; uint4 u; } pk;
            #pragma unroll
            for (int j = 0; j < 8; ++j) {
                Braw[(size_t)chunk*(CHUNK*D_STATE) + (size_t)(t0+j)*D_STATE + n] = tbf(o[j]);
                pk.ob[j] = tbf(o[j] * wvec[rowbase + t0 + j]);
            }
            *(uint4*)(Bw + (size_t)chunk*(D_STATE*CHUNK) + (size_t)n*CHUNK + t0) = pk.u;
        } else {
            #pragma unroll
            for (int j = 0; j < 8; ++j) {
                Craw[(size_t)chunk*(CHUNK*D_STATE) + (size_t)(t0+j)*D_STATE + n] = tbf(o[j]);
                A2[(size_t)chunk*(CHUNK*256) + (size_t)(t0+j)*256 + 128 + n] =
                    tbf(o[j] * esvec[rowbase + t0 + j]);
            }
        }
    }
}

// ---------- sequential carry over 16 chunks/batch, writes Hprev into B2[:, 128:256] ----------
__global__ void k_carry(const bf16* __restrict__ dH, const float* __restrict__ Pc,
                        bf16* __restrict__ B2)
{
    int idx = blockIdx.x * 256 + threadIdx.x;   // p*128+n
    int b = blockIdx.y;
    int p = idx >> 7, n = idx & 127;
    float h = 0.f;
    for (int c = 0; c < CPB; ++c) {
        int bi = b * CPB + c;
        B2[(size_t)bi * (D_INNER*256) + (size_t)p * 256 + 128 + n] = tbf(h);
        h = Pc[bi] * h + fbf(dH[(size_t)bi * (D_INNER*D_STATE) + idx]);
    }
}

// ---------- gate (silu(z)) + RMSNorm, in-place on bf16 y ----------
__global__ __launch_bounds__(256) void k_gate_norm(
    bf16* __restrict__ y, const bf16* __restrict__ zb,
    const float* __restrict__ norm_w)
{
    int row = blockIdx.x;
    int tid = threadIdx.x;
    bf16* yr = y + (size_t)row * D_INNER;
    const bf16* zr = zb + (size_t)row * D_INNER;
    union { bf16 b[4]; uint2 u; } ly, lz;
    ly.u = *(const uint2*)(yr + tid * 4);
    lz.u = *(const uint2*)(zr + tid * 4);
    float v[4], ss = 0.f;
    #pragma unroll
    for (int j = 0; j < 4; ++j) {
        float z = fbf(lz.b[j]);
        v[j] = fbf(ly.b[j]) * z / (1.f + expf(-z));
        ss += v[j] * v[j];
    }
    #pragma unroll
    for (int off = 32; off; off >>= 1) ss += __shfl_xor(ss, off);
    __shared__ float wsum[4];
    if ((tid & 63) == 0) wsum[tid >> 6] = ss;
    __syncthreads();
    float tot   = wsum[0] + wsum[1] + wsum[2] + wsum[3];
    float scale = rsqrtf(tot * (1.f / D_INNER) + EPS_RMS);
    union { bf16 b[4]; uint2 u; } po;
    #pragma unroll
    for (int j = 0; j < 4; ++j)
        po.b[j] = tbf(v[j] * scale * norm_w[tid*4 + j]);
    *(uint2*)(yr + tid * 4) = po.u;
}

extern "C" void kernel_launch(void* const* d_in, const int* in_sizes, int n_in,
                              void* d_out, int out_size, void* d_ws, size_t ws_size,
                              hipStream_t stream)
{
    const float* x       = (const float*)d_in[0];
    const float* rnn     = (const float*)d_in[1];
    const float* W_in    = (const float*)d_in[2];
    const float* conv_w  = (const float*)d_in[3];
    const float* conv_b  = (const float*)d_in[4];
    const float* dt_bias = (const float*)d_in[5];
    const float* A_log   = (const float*)d_in[6];
    const float* Dp      = (const float*)d_in[7];
    const float* norm_w  = (const float*)d_in[8];
    const float* W_out   = (const float*)d_in[9];
    float* out = (float*)d_out;

    char* ws = (char*)d_ws;
    size_t off = 0;
    auto alloc = [&](size_t bytes) { void* p = ws + off; off += (bytes + 255) & ~255ULL; return p; };

    // ---- persistent ----
    bf16*  W_inbT  = (bf16*) alloc((size_t)NPROJ * D_MODEL * 2);        // 2.36M
    bf16*  W_outbT = (bf16*) alloc((size_t)D_MODEL * D_INNER * 2);      // 1.05M
    float* dts     = (float*)alloc((size_t)NROWS * 4);
    float* svec    = (float*)alloc((size_t)NROWS * 4);
    float* wvec    = (float*)alloc((size_t)NROWS * 4);
    float* esvec   = (float*)alloc((size_t)NROWS * 4);
    float* Pc      = (float*)alloc((size_t)NCHUNK * 4);
    bf16*  zb      = (bf16*) alloc((size_t)NROWS * D_INNER * 2);        // 33.5M
    bf16*  A2      = (bf16*) alloc((size_t)NCHUNK * CHUNK * 256 * 2);   // 8.4M  [Sm | Cs]
    bf16*  B2      = (bf16*) alloc((size_t)NCHUNK * D_INNER * 256 * 2); // 67.1M [Xt | Hprev]
    bf16*  Bw      = (bf16*) alloc((size_t)NCHUNK * D_STATE * CHUNK * 2);  // 4.2M
    bf16*  Braw    = (bf16*) alloc((size_t)NCHUNK * CHUNK * D_STATE * 2); // 4.2M
    bf16*  Craw    = (bf16*) alloc((size_t)NCHUNK * CHUNK * D_STATE * 2); // 4.2M
    // ---- aliased region A (50.3M): xb[0:16.8]+dH[16.8:50.3], later ybf[0:33.5] ----
    char* RA = (char*)alloc((size_t)NROWS * D_MODEL * 2 + (size_t)NROWS * D_INNER * 2);
    bf16*  xb   = (bf16*)RA;                                   // [dtcvt -> GEMM1]
    bf16*  dH   = (bf16*)(RA + (size_t)NROWS * D_MODEL * 2);   // [dH-GEMM -> carry]
    bf16*  ybf  = (bf16*)RA;                                   // [Y-GEMM -> norm -> GEMM2]
    // ---- aliased region B (41.9M): xBCin [GEMM1 -> convs] ----
    bf16*  xBCin = (bf16*)alloc((size_t)NROWS * CONV_DIM * 2);
    // total ~208 MB (234.3 proven available in R3)

    // 1. fused convert + dt GEMV; weight transposes; cumsum prep
    k_dtcvt<<<NROWS / 4, 256, 0, stream>>>(x, W_in, dt_bias, xb, dts);
    k_transpose_cvt<<<dim3(D_MODEL/32, NPROJ/32), dim3(32, 8), 0, stream>>>(
        W_in, W_inbT, NPROJ, D_MODEL, D_IN_PROJ);
    k_transpose_cvt<<<dim3(D_INNER/32, D_MODEL/32), dim3(32, 8), 0, stream>>>(
        W_out, W_outbT, D_MODEL, D_INNER, D_MODEL);
    k_prep<<<NCHUNK, CHUNK, 0, stream>>>(dts, A_log, svec, wvec, esvec, Pc);

    // 2. in-projection GEMM with split output
    k_gemm_in<<<dim3(NROWS/128, NPROJ/128), 256, 0, stream>>>(xb, W_inbT, zb, xBCin, D_MODEL);

    // 3. conv + silu, fused with operand builds
    k_conv_x<<<dim3(8, NCHUNK), 256, 0, stream>>>(xBCin, conv_w, conv_b, B2);
    k_conv_bc<<<NCHUNK, 256, 0, stream>>>(xBCin, conv_w, conv_b, wvec, esvec,
                                          Braw, Craw, Bw, A2);

    // 4. G = C @ B^T with fused mask/decay/+D epilogue -> A2[:, 0:128]
    k_bgemm<2><<<dim3(1, 1, NCHUNK), 256, 0, stream>>>(
        Craw, D_STATE, (size_t)CHUNK*D_STATE,
        Braw, D_STATE, (size_t)CHUNK*D_STATE,
        A2, 256, (size_t)CHUNK*256, CHUNK, svec, dts, Dp);

    // 5. dH = X^T @ Bw^T  (A = Xt region of B2, lda=256)
    k_bgemm<1><<<dim3(D_INNER/128, 1, NCHUNK), 256, 0, stream>>>(
        B2, 256, (size_t)D_INNER*256,
        Bw, CHUNK, (size_t)D_STATE*CHUNK,
        dH, D_STATE, (size_t)D_INNER*D_STATE, CHUNK, nullptr, nullptr, nullptr);

    // 6. carry states -> Hprev region of B2
    k_carry<<<dim3(D_INNER*D_STATE/256, BATCH), 256, 0, stream>>>(dH, Pc, B2);

    // 7. Y = [Sm|Cs] @ [Xt|Hprev]^T  (K=256) -> ybf (bf16)
    k_bgemm<1><<<dim3(1, D_INNER/128, NCHUNK), 256, 0, stream>>>(
        A2, 256, (size_t)CHUNK*256,
        B2, 256, (size_t)D_INNER*256,
        ybf, D_INNER, (size_t)CHUNK*D_INNER, 256, nullptr, nullptr, nullptr);

    // 8. gate + RMSNorm in-place on ybf
    k_gate_norm<<<NROWS, 256, 0, stream>>>(ybf, zb, norm_w);

    // 9. out-projection GEMM -> d_out
    k_bgemm<0><<<dim3(NROWS/128, D_MODEL/128, 1), 256, 0, stream>>>(
        ybf, D_INNER, 0, W_outbT, D_INNER, 0, out, D_MODEL, 0, D_INNER,
        nullptr, nullptr, nullptr);

    // 10. rnn_state passthrough
    hipMemcpyAsync(out + (size_t)NROWS * D_MODEL, rnn,
                   (size_t)BATCH * D_MODEL * sizeof(float),
                   hipMemcpyDeviceToDevice, stream);
}

// Round 5
// 326.931 us; speedup vs baseline: 1.1096x; 1.1096x over previous
//
#include <hip/hip_runtime.h>
#include <hip/hip_bf16.h>
#include <math.h>

#define D_MODEL 512
#define D_INNER 1024
#define D_STATE 128
#define CONV_DIM (D_INNER + 2*D_STATE)        // 1280
#define D_IN_PROJ (2*D_INNER + 2*D_STATE + 1) // 2305
#define NPROJ 2304                            // z + xBC cols (dt col via GEMV)
#define BATCH 8
#define SEQ 2048
#define NROWS (BATCH*SEQ)                     // 16384
#define CHUNK 128
#define NCHUNK (NROWS/CHUNK)                  // 128 total (16 per batch)
#define CPB (SEQ/CHUNK)                       // 16 chunks per batch
#define EPS_RMS 1e-5f

typedef __hip_bfloat16 bf16;
typedef __attribute__((ext_vector_type(8))) short short8;
typedef __attribute__((ext_vector_type(4))) float f32x4;

__device__ __forceinline__ float fbf(bf16 v) { return __bfloat162float(v); }
__device__ __forceinline__ bf16 tbf(float v) { return __float2bfloat16(v); }

// async global->LDS, 16B per lane; LDS dest is wave-uniform base + lane*16
__device__ __forceinline__ void gl2lds16(const bf16* g, bf16* l) {
    __builtin_amdgcn_global_load_lds(
        (const __attribute__((address_space(1))) unsigned int*)g,
        (__attribute__((address_space(3))) unsigned int*)l, 16, 0, 0);
}

// LDS swizzle: logical (row r, 16B-group g) stored at group (g ^ (r&7)).
// Staging lane i sits at (r=i>>3, g'=i&7) -> fetches global group (i&7)^(i>>3).
// Quad-group reads then spread across all 8 groups (2-way aliasing = free, m136).

// ---------- transpose + convert: dst[r][c] = bf16(src[c*sstride + r]) ----------
__global__ void k_transpose_cvt(const float* __restrict__ src, bf16* __restrict__ dst,
                                int R, int C, int sstride) {
    __shared__ float tile[32][33];
    int c0 = blockIdx.x * 32, r0 = blockIdx.y * 32;
    int tx = threadIdx.x, ty = threadIdx.y;
    #pragma unroll
    for (int i = 0; i < 32; i += 8)
        tile[ty + i][tx] = src[(size_t)(c0 + ty + i) * sstride + (r0 + tx)];
    __syncthreads();
    #pragma unroll
    for (int i = 0; i < 32; i += 8)
        dst[(size_t)(r0 + ty + i) * C + (c0 + tx)] = tbf(tile[tx][ty + i]);
}

// ---------- fused x->bf16 convert + dt GEMV + softplus ----------
__global__ __launch_bounds__(256) void k_dtcvt(
    const float* __restrict__ x, const float* __restrict__ W_in,
    const float* __restrict__ dt_bias,
    bf16* __restrict__ xb, float* __restrict__ dts)
{
    __shared__ float wcol[D_MODEL];
    int tid = threadIdx.x;
    wcol[tid]       = W_in[(size_t)tid * D_IN_PROJ + 2304];
    wcol[tid + 256] = W_in[(size_t)(tid + 256) * D_IN_PROJ + 2304];
    __syncthreads();
    int row  = blockIdx.x * 4 + (tid >> 6);
    int lane = tid & 63;
    const float* xr = x + (size_t)row * D_MODEL;
    float4 a = *(const float4*)(xr + lane * 8);
    float4 b = *(const float4*)(xr + lane * 8 + 4);
    union { bf16 o[8]; uint4 u; } pk;
    pk.o[0]=tbf(a.x); pk.o[1]=tbf(a.y); pk.o[2]=tbf(a.z); pk.o[3]=tbf(a.w);
    pk.o[4]=tbf(b.x); pk.o[5]=tbf(b.y); pk.o[6]=tbf(b.z); pk.o[7]=tbf(b.w);
    *(uint4*)(xb + (size_t)row * D_MODEL + lane * 8) = pk.u;
    const float* wc = wcol + lane * 8;
    float s = a.x*wc[0]+a.y*wc[1]+a.z*wc[2]+a.w*wc[3]
            + b.x*wc[4]+b.y*wc[5]+b.z*wc[6]+b.w*wc[7];
    #pragma unroll
    for (int off = 32; off; off >>= 1) s += __shfl_xor(s, off);
    if (lane == 0) {
        float raw = s + dt_bias[0];
        dts[row] = raw > 20.f ? raw : log1pf(expf(raw));
    }
}

// ---------- batched NT GEMM, 128x128 tile, BK=64, global_load_lds + XOR swizzle ----------
// MODE 0: fp32 out.  MODE 1: bf16 out.  MODE 2: Sm-fused bf16 out (mask*decay*dt + D diag).
template<int MODE>
__global__ __launch_bounds__(256) void k_bgemm(
    const bf16* __restrict__ A, int lda, size_t sA,
    const bf16* __restrict__ Bt, int ldb, size_t sB,
    void* __restrict__ Cv, int ldc, size_t sC, int K,
    const float* __restrict__ svec, const float* __restrict__ dts,
    const float* __restrict__ Dp)
{
    constexpr int BK = 64;
    __shared__ __align__(16) bf16 As[128][BK];
    __shared__ __align__(16) bf16 Bs[128][BK];
    const int tid = threadIdx.x, lane = tid & 63, wave = tid >> 6;
    const int wm = (wave & 1) * 64, wn = (wave >> 1) * 64;
    const int lr = lane & 15, quad = lane >> 4;
    const int rx = lr & 7;               // read-side swizzle term
    const size_t bm = (size_t)blockIdx.x * 128;
    const size_t bn = (size_t)blockIdx.y * 128;
    const size_t bi = blockIdx.z;
    A  += bi * sA;
    Bt += bi * sB;
    const int srow = lane >> 3;                       // staging row within 8-row group
    const int scol = (((lane & 7) ^ srow) << 3);      // swizzled 16B column group

    f32x4 acc[4][4];
    #pragma unroll
    for (int i = 0; i < 4; ++i)
        #pragma unroll
        for (int j = 0; j < 4; ++j) acc[i][j] = (f32x4){0.f,0.f,0.f,0.f};

    for (int k0 = 0; k0 < K; k0 += BK) {
        __syncthreads();
        #pragma unroll
        for (int q = 0; q < 4; ++q) {
            int rg = wave * 32 + q * 8;
            gl2lds16(A  + (bm + rg + srow) * lda + k0 + scol, &As[rg][0]);
            gl2lds16(Bt + (bn + rg + srow) * ldb + k0 + scol, &Bs[rg][0]);
        }
        __syncthreads();
        #pragma unroll
        for (int ks = 0; ks < BK; ks += 32) {
            const int off = ((((ks >> 3) + quad) ^ rx) << 3);
            short8 af[4], bg[4];
            #pragma unroll
            for (int i = 0; i < 4; ++i)
                af[i] = *(const short8*)(&As[wm + i*16 + lr][off]);
            #pragma unroll
            for (int j = 0; j < 4; ++j)
                bg[j] = *(const short8*)(&Bs[wn + j*16 + lr][off]);
            #pragma unroll
            for (int i = 0; i < 4; ++i)
                #pragma unroll
                for (int j = 0; j < 4; ++j)
                    acc[i][j] = __builtin_amdgcn_mfma_f32_16x16x32_bf16(af[i], bg[j], acc[i][j], 0,0,0);
        }
    }
    const int rb = (int)bi * CHUNK;
    #pragma unroll
    for (int i = 0; i < 4; ++i)
        #pragma unroll
        for (int j = 0; j < 4; ++j)
            #pragma unroll
            for (int r = 0; r < 4; ++r) {
                size_t row = bm + wm + i*16 + quad*4 + r;
                size_t col = bn + wn + j*16 + lr;
                float v = acc[i][j][r];
                if (MODE == 0) {
                    ((float*)Cv + bi*sC)[row * ldc + col] = v;
                } else if (MODE == 1) {
                    ((bf16*)Cv + bi*sC)[row * ldc + col] = tbf(v);
                } else {
                    float o = 0.f;
                    if (col <= row) {
                        o = v * expf(svec[rb + row] - svec[rb + col]) * dts[rb + col];
                        if (col == row) o += Dp[0];
                    }
                    ((bf16*)Cv + bi*sC)[row * ldc + col] = tbf(o);
                }
            }
}

// ---------- GEMM1 with split output: cols<1024 -> zb, else xBCin ----------
__global__ __launch_bounds__(256) void k_gemm_in(
    const bf16* __restrict__ A, const bf16* __restrict__ Bt,
    bf16* __restrict__ zb, bf16* __restrict__ xBCin, int K)
{
    constexpr int BK = 64;
    __shared__ __align__(16) bf16 As[128][BK];
    __shared__ __align__(16) bf16 Bs[128][BK];
    const int tid = threadIdx.x, lane = tid & 63, wave = tid >> 6;
    const int wm = (wave & 1) * 64, wn = (wave >> 1) * 64;
    const int lr = lane & 15, quad = lane >> 4;
    const int rx = lr & 7;
    const size_t bm = (size_t)blockIdx.x * 128;
    const int bn = blockIdx.y * 128;
    const int srow = lane >> 3;
    const int scol = (((lane & 7) ^ srow) << 3);

    f32x4 acc[4][4];
    #pragma unroll
    for (int i = 0; i < 4; ++i)
        #pragma unroll
        for (int j = 0; j < 4; ++j) acc[i][j] = (f32x4){0.f,0.f,0.f,0.f};

    for (int k0 = 0; k0 < K; k0 += BK) {
        __syncthreads();
        #pragma unroll
        for (int q = 0; q < 4; ++q) {
            int rg = wave * 32 + q * 8;
            gl2lds16(A  + (bm + rg + srow) * K + k0 + scol, &As[rg][0]);
            gl2lds16(Bt + ((size_t)bn + rg + srow) * K + k0 + scol, &Bs[rg][0]);
        }
        __syncthreads();
        #pragma unroll
        for (int ks = 0; ks < BK; ks += 32) {
            const int off = ((((ks >> 3) + quad) ^ rx) << 3);
            short8 af[4], bg[4];
            #pragma unroll
            for (int i = 0; i < 4; ++i)
                af[i] = *(const short8*)(&As[wm + i*16 + lr][off]);
            #pragma unroll
            for (int j = 0; j < 4; ++j)
                bg[j] = *(const short8*)(&Bs[wn + j*16 + lr][off]);
            #pragma unroll
            for (int i = 0; i < 4; ++i)
                #pragma unroll
                for (int j = 0; j < 4; ++j)
                    acc[i][j] = __builtin_amdgcn_mfma_f32_16x16x32_bf16(af[i], bg[j], acc[i][j], 0,0,0);
        }
    }
    #pragma unroll
    for (int i = 0; i < 4; ++i)
        #pragma unroll
        for (int j = 0; j < 4; ++j)
            #pragma unroll
            for (int r = 0; r < 4; ++r) {
                size_t row = bm + wm + i*16 + quad*4 + r;
                int col = bn + wn + j*16 + lr;
                float v = acc[i][j][r];
                if (col < D_INNER) zb[row * D_INNER + col] = tbf(v);
                else xBCin[row * CONV_DIM + (col - D_INNER)] = tbf(v);
            }
}

// ---------- per-chunk cumsum of a_t = A*dt, decay factors ----------
__global__ void k_prep(const float* __restrict__ dts, const float* __restrict__ A_log,
                       float* __restrict__ svec, float* __restrict__ wvec,
                       float* __restrict__ esvec, float* __restrict__ Pc)
{
    int chunk = blockIdx.x, t = threadIdx.x;  // 128 threads
    int row = chunk * CHUNK + t;
    float A = -expf(A_log[0]);
    __shared__ float sh[CHUNK];
    sh[t] = A * dts[row];
    __syncthreads();
    for (int off = 1; off < CHUNK; off <<= 1) {
        float v = (t >= off) ? sh[t - off] : 0.f;
        __syncthreads();
        sh[t] += v;
        __syncthreads();
    }
    float s = sh[t], sL = sh[CHUNK - 1];
    svec[row]  = s;
    wvec[row]  = expf(sL - s) * dts[row];
    esvec[row] = expf(s);
    if (t == CHUNK - 1) Pc[chunk] = expf(sL);
}

// ---------- conv+silu for x-region, writes Xt directly into B2[:, 0:128] ----------
__global__ __launch_bounds__(256) void k_conv_x(
    const bf16* __restrict__ xBCin, const float* __restrict__ conv_w,
    const float* __restrict__ conv_b, bf16* __restrict__ B2)
{
    __shared__ __align__(16) bf16 Ls[131][128];
    const int chunk = blockIdx.y;
    const int p0 = blockIdx.x * 128;
    const int tid = threadIdx.x;
    const bool first = (chunk % CPB) == 0;
    const size_t rowbase = (size_t)chunk * CHUNK;
    for (int i = tid; i < 131 * 16; i += 256) {
        int r = i >> 4, cg = (i & 15) << 3;
        uint4 v = (uint4){0,0,0,0};
        if (!(first && r < 3))
            v = *(const uint4*)(xBCin + (rowbase + r - 3) * CONV_DIM + p0 + cg);
        *(uint4*)(&Ls[r][cg]) = v;
    }
    __syncthreads();
    const int p = tid & 127;
    const int half = tid >> 7;
    const int ch = p0 + p;
    float4 w = *(const float4*)(conv_w + ch * 4);
    float bias = conv_b[ch];
    bf16* outrow = B2 + (size_t)chunk * (D_INNER * 256) + (size_t)ch * 256;
    float xv[11];
    #pragma unroll
    for (int i = 0; i < 3; ++i) xv[i + 8] = fbf(Ls[half * 64 + i][p]);
    for (int v = 0; v < 8; ++v) {
        int t0 = half * 64 + v * 8;
        xv[0]=xv[8]; xv[1]=xv[9]; xv[2]=xv[10];
        #pragma unroll
        for (int i = 3; i < 11; ++i) xv[i] = fbf(Ls[t0 + i][p]);
        union { bf16 o[8]; uint4 u; } pk;
        #pragma unroll
        for (int j = 0; j < 8; ++j) {
            float a = bias + w.x*xv[j] + w.y*xv[j+1] + w.z*xv[j+2] + w.w*xv[j+3];
            pk.o[j] = tbf(a / (1.f + expf(-a)));
        }
        *(uint4*)(outrow + t0) = pk.u;
    }
}

// ---------- conv+silu for B/C region: raw B, raw C, scaled Bw^T, scaled Cs ----------
__global__ __launch_bounds__(256) void k_conv_bc(
    const bf16* __restrict__ xBCin, const float* __restrict__ conv_w,
    const float* __restrict__ conv_b, const float* __restrict__ wvec,
    const float* __restrict__ esvec,
    bf16* __restrict__ Braw, bf16* __restrict__ Craw,
    bf16* __restrict__ Bw, bf16* __restrict__ A2)
{
    __shared__ __align__(16) bf16 Ls[131][256];
    const int chunk = blockIdx.x;
    const bool first = (chunk % CPB) == 0;
    const size_t rowbase = (size_t)chunk * CHUNK;
    for (int i = threadIdx.x; i < 131 * 32; i += 256) {
        int r = i >> 5, cg = (i & 31) << 3;
        uint4 v = (uint4){0,0,0,0};
        if (!(first && r < 3))
            v = *(const uint4*)(xBCin + (rowbase + r - 3) * CONV_DIM + D_INNER + cg);
        *(uint4*)(&Ls[r][cg]) = v;
    }
    __syncthreads();
    const int n   = threadIdx.x & 127;
    const int reg = threadIdx.x >> 7;  // 0 = B, 1 = C
    const int cl  = reg * 128 + n;
    const int ch  = D_INNER + cl;
    float4 w = *(const float4*)(conv_w + ch * 4);
    float bias = conv_b[ch];
    float xv[11];
    #pragma unroll
    for (int i = 0; i < 3; ++i) xv[i + 8] = fbf(Ls[i][cl]);
    for (int v = 0; v < 16; ++v) {
        int t0 = v * 8;
        xv[0]=xv[8]; xv[1]=xv[9]; xv[2]=xv[10];
        #pragma unroll
        for (int i = 3; i < 11; ++i) xv[i] = fbf(Ls[t0 + i][cl]);
        float o[8];
        #pragma unroll
        for (int j = 0; j < 8; ++j) {
            float a = bias + w.x*xv[j] + w.y*xv[j+1] + w.z*xv[j+2] + w.w*xv[j+3];
            o[j] = a / (1.f + expf(-a));
        }
        if (reg == 0) {
            union { bf16 ob[8]; uint4 u; } pk;
            #pragma unroll
            for (int j = 0; j < 8; ++j) {
                Braw[(size_t)chunk*(CHUNK*D_STATE) + (size_t)(t0+j)*D_STATE + n] = tbf(o[j]);
                pk.ob[j] = tbf(o[j] * wvec[rowbase + t0 + j]);
            }
            *(uint4*)(Bw + (size_t)chunk*(D_STATE*CHUNK) + (size_t)n*CHUNK + t0) = pk.u;
        } else {
            #pragma unroll
            for (int j = 0; j < 8; ++j) {
                Craw[(size_t)chunk*(CHUNK*D_STATE) + (size_t)(t0+j)*D_STATE + n] = tbf(o[j]);
                A2[(size_t)chunk*(CHUNK*256) + (size_t)(t0+j)*256 + 128 + n] =
                    tbf(o[j] * esvec[rowbase + t0 + j]);
            }
        }
    }
}

// ---------- sequential carry over 16 chunks/batch, writes Hprev into B2[:, 128:256] ----------
__global__ void k_carry(const bf16* __restrict__ dH, const float* __restrict__ Pc,
                        bf16* __restrict__ B2)
{
    int idx = blockIdx.x * 256 + threadIdx.x;   // p*128+n
    int b = blockIdx.y;
    int p = idx >> 7, n = idx & 127;
    float h = 0.f;
    for (int c = 0; c < CPB; ++c) {
        int bi = b * CPB + c;
        B2[(size_t)bi * (D_INNER*256) + (size_t)p * 256 + 128 + n] = tbf(h);
        h = Pc[bi] * h + fbf(dH[(size_t)bi * (D_INNER*D_STATE) + idx]);
    }
}

// ---------- gate (silu(z)) + RMSNorm, in-place on bf16 y ----------
__global__ __launch_bounds__(256) void k_gate_norm(
    bf16* __restrict__ y, const bf16* __restrict__ zb,
    const float* __restrict__ norm_w)
{
    int row = blockIdx.x;
    int tid = threadIdx.x;
    bf16* yr = y + (size_t)row * D_INNER;
    const bf16* zr = zb + (size_t)row * D_INNER;
    union { bf16 b[4]; uint2 u; } ly, lz;
    ly.u = *(const uint2*)(yr + tid * 4);
    lz.u = *(const uint2*)(zr + tid * 4);
    float v[4], ss = 0.f;
    #pragma unroll
    for (int j = 0; j < 4; ++j) {
        float z = fbf(lz.b[j]);
        v[j] = fbf(ly.b[j]) * z / (1.f + expf(-z));
        ss += v[j] * v[j];
    }
    #pragma unroll
    for (int off = 32; off; off >>= 1) ss += __shfl_xor(ss, off);
    __shared__ float wsum[4];
    if ((tid & 63) == 0) wsum[tid >> 6] = ss;
    __syncthreads();
    float tot   = wsum[0] + wsum[1] + wsum[2] + wsum[3];
    float scale = rsqrtf(tot * (1.f / D_INNER) + EPS_RMS);
    union { bf16 b[4]; uint2 u; } po;
    #pragma unroll
    for (int j = 0; j < 4; ++j)
        po.b[j] = tbf(v[j] * scale * norm_w[tid*4 + j]);
    *(uint2*)(yr + tid * 4) = po.u;
}

extern "C" void kernel_launch(void* const* d_in, const int* in_sizes, int n_in,
                              void* d_out, int out_size, void* d_ws, size_t ws_size,
                              hipStream_t stream)
{
    const float* x       = (const float*)d_in[0];
    const float* rnn     = (const float*)d_in[1];
    const float* W_in    = (const float*)d_in[2];
    const float* conv_w  = (const float*)d_in[3];
    const float* conv_b  = (const float*)d_in[4];
    const float* dt_bias = (const float*)d_in[5];
    const float* A_log   = (const float*)d_in[6];
    const float* Dp      = (const float*)d_in[7];
    const float* norm_w  = (const float*)d_in[8];
    const float* W_out   = (const float*)d_in[9];
    float* out = (float*)d_out;

    char* ws = (char*)d_ws;
    size_t off = 0;
    auto alloc = [&](size_t bytes) { void* p = ws + off; off += (bytes + 255) & ~255ULL; return p; };

    // ---- persistent ----
    bf16*  W_inbT  = (bf16*) alloc((size_t)NPROJ * D_MODEL * 2);        // 2.36M
    bf16*  W_outbT = (bf16*) alloc((size_t)D_MODEL * D_INNER * 2);      // 1.05M
    float* dts     = (float*)alloc((size_t)NROWS * 4);
    float* svec    = (float*)alloc((size_t)NROWS * 4);
    float* wvec    = (float*)alloc((size_t)NROWS * 4);
    float* esvec   = (float*)alloc((size_t)NROWS * 4);
    float* Pc      = (float*)alloc((size_t)NCHUNK * 4);
    bf16*  zb      = (bf16*) alloc((size_t)NROWS * D_INNER * 2);        // 33.5M
    bf16*  A2      = (bf16*) alloc((size_t)NCHUNK * CHUNK * 256 * 2);   // 8.4M  [Sm | Cs]
    bf16*  B2      = (bf16*) alloc((size_t)NCHUNK * D_INNER * 256 * 2); // 67.1M [Xt | Hprev]
    bf16*  Bw      = (bf16*) alloc((size_t)NCHUNK * D_STATE * CHUNK * 2);  // 4.2M
    bf16*  Braw    = (bf16*) alloc((size_t)NCHUNK * CHUNK * D_STATE * 2); // 4.2M
    bf16*  Craw    = (bf16*) alloc((size_t)NCHUNK * CHUNK * D_STATE * 2); // 4.2M
    // ---- aliased region A (50.3M): xb[0:16.8]+dH[16.8:50.3], later ybf[0:33.5] ----
    char* RA = (char*)alloc((size_t)NROWS * D_MODEL * 2 + (size_t)NROWS * D_INNER * 2);
    bf16*  xb   = (bf16*)RA;                                   // [dtcvt -> GEMM1]
    bf16*  dH   = (bf16*)(RA + (size_t)NROWS * D_MODEL * 2);   // [dH-GEMM -> carry]
    bf16*  ybf  = (bf16*)RA;                                   // [Y-GEMM -> norm -> GEMM2]
    // ---- aliased region B (41.9M): xBCin [GEMM1 -> convs] ----
    bf16*  xBCin = (bf16*)alloc((size_t)NROWS * CONV_DIM * 2);
    // total ~208 MB

    // 1. fused convert + dt GEMV; weight transposes; cumsum prep
    k_dtcvt<<<NROWS / 4, 256, 0, stream>>>(x, W_in, dt_bias, xb, dts);
    k_transpose_cvt<<<dim3(D_MODEL/32, NPROJ/32), dim3(32, 8), 0, stream>>>(
        W_in, W_inbT, NPROJ, D_MODEL, D_IN_PROJ);
    k_transpose_cvt<<<dim3(D_INNER/32, D_MODEL/32), dim3(32, 8), 0, stream>>>(
        W_out, W_outbT, D_MODEL, D_INNER, D_MODEL);
    k_prep<<<NCHUNK, CHUNK, 0, stream>>>(dts, A_log, svec, wvec, esvec, Pc);

    // 2. in-projection GEMM with split output
    k_gemm_in<<<dim3(NROWS/128, NPROJ/128), 256, 0, stream>>>(xb, W_inbT, zb, xBCin, D_MODEL);

    // 3. conv + silu, fused with operand builds
    k_conv_x<<<dim3(8, NCHUNK), 256, 0, stream>>>(xBCin, conv_w, conv_b, B2);
    k_conv_bc<<<NCHUNK, 256, 0, stream>>>(xBCin, conv_w, conv_b, wvec, esvec,
                                          Braw, Craw, Bw, A2);

    // 4. G = C @ B^T with fused mask/decay/+D epilogue -> A2[:, 0:128]
    k_bgemm<2><<<dim3(1, 1, NCHUNK), 256, 0, stream>>>(
        Craw, D_STATE, (size_t)CHUNK*D_STATE,
        Braw, D_STATE, (size_t)CHUNK*D_STATE,
        A2, 256, (size_t)CHUNK*256, CHUNK, svec, dts, Dp);

    // 5. dH = X^T @ Bw^T  (A = Xt region of B2, lda=256)
    k_bgemm<1><<<dim3(D_INNER/128, 1, NCHUNK), 256, 0, stream>>>(
        B2, 256, (size_t)D_INNER*256,
        Bw, CHUNK, (size_t)D_STATE*CHUNK,
        dH, D_STATE, (size_t)D_INNER*D_STATE, CHUNK, nullptr, nullptr, nullptr);

    // 6. carry states -> Hprev region of B2
    k_carry<<<dim3(D_INNER*D_STATE/256, BATCH), 256, 0, stream>>>(dH, Pc, B2);

    // 7. Y = [Sm|Cs] @ [Xt|Hprev]^T  (K=256) -> ybf (bf16)
    k_bgemm<1><<<dim3(1, D_INNER/128, NCHUNK), 256, 0, stream>>>(
        A2, 256, (size_t)CHUNK*256,
        B2, 256, (size_t)D_INNER*256,
        ybf, D_INNER, (size_t)CHUNK*D_INNER, 256, nullptr, nullptr, nullptr);

    // 8. gate + RMSNorm in-place on ybf
    k_gate_norm<<<NROWS, 256, 0, stream>>>(ybf, zb, norm_w);

    // 9. out-projection GEMM -> d_out
    k_bgemm<0><<<dim3(NROWS/128, D_MODEL/128, 1), 256, 0, stream>>>(
        ybf, D_INNER, 0, W_outbT, D_INNER, 0, out, D_MODEL, 0, D_INNER,
        nullptr, nullptr, nullptr);

    // 10. rnn_state passthrough
    hipMemcpyAsync(out + (size_t)NROWS * D_MODEL, rnn,
                   (size_t)BATCH * D_MODEL * sizeof(float),
                   hipMemcpyDeviceToDevice, stream);
}

// Round 6
// 323.125 us; speedup vs baseline: 1.1227x; 1.0118x over previous
//
#include <hip/hip_runtime.h>
#include <hip/hip_bf16.h>
#include <math.h>

#define D_MODEL 512
#define D_INNER 1024
#define D_STATE 128
#define CONV_DIM (D_INNER + 2*D_STATE)        // 1280
#define D_IN_PROJ (2*D_INNER + 2*D_STATE + 1) // 2305
#define NPROJ 2304                            // z + xBC cols (dt col via GEMV)
#define BATCH 8
#define SEQ 2048
#define NROWS (BATCH*SEQ)                     // 16384
#define CHUNK 128
#define NCHUNK (NROWS/CHUNK)                  // 128 total (16 per batch)
#define CPB (SEQ/CHUNK)                       // 16 chunks per batch
#define EPS_RMS 1e-5f

typedef __hip_bfloat16 bf16;
typedef __attribute__((ext_vector_type(8))) short short8;
typedef __attribute__((ext_vector_type(4))) float f32x4;

__device__ __forceinline__ float fbf(bf16 v) { return __bfloat162float(v); }
__device__ __forceinline__ bf16 tbf(float v) { return __float2bfloat16(v); }

// async global->LDS, 16B per lane; LDS dest is wave-uniform base + lane*16
__device__ __forceinline__ void gl2lds16(const bf16* g, bf16* l) {
    __builtin_amdgcn_global_load_lds(
        (const __attribute__((address_space(1))) unsigned int*)g,
        (__attribute__((address_space(3))) unsigned int*)l, 16, 0, 0);
}

// ---------- transpose + convert: dst[r][c] = bf16(src[c*sstride + r]) ----------
__global__ void k_transpose_cvt(const float* __restrict__ src, bf16* __restrict__ dst,
                                int R, int C, int sstride) {
    __shared__ float tile[32][33];
    int c0 = blockIdx.x * 32, r0 = blockIdx.y * 32;
    int tx = threadIdx.x, ty = threadIdx.y;
    #pragma unroll
    for (int i = 0; i < 32; i += 8)
        tile[ty + i][tx] = src[(size_t)(c0 + ty + i) * sstride + (r0 + tx)];
    __syncthreads();
    #pragma unroll
    for (int i = 0; i < 32; i += 8)
        dst[(size_t)(r0 + ty + i) * C + (c0 + tx)] = tbf(tile[tx][ty + i]);
}

// ---------- fused x->bf16 convert + dt GEMV + softplus ----------
__global__ __launch_bounds__(256) void k_dtcvt(
    const float* __restrict__ x, const float* __restrict__ W_in,
    const float* __restrict__ dt_bias,
    bf16* __restrict__ xb, float* __restrict__ dts)
{
    __shared__ float wcol[D_MODEL];
    int tid = threadIdx.x;
    wcol[tid]       = W_in[(size_t)tid * D_IN_PROJ + 2304];
    wcol[tid + 256] = W_in[(size_t)(tid + 256) * D_IN_PROJ + 2304];
    __syncthreads();
    int row  = blockIdx.x * 4 + (tid >> 6);
    int lane = tid & 63;
    const float* xr = x + (size_t)row * D_MODEL;
    float4 a = *(const float4*)(xr + lane * 8);
    float4 b = *(const float4*)(xr + lane * 8 + 4);
    union { bf16 o[8]; uint4 u; } pk;
    pk.o[0]=tbf(a.x); pk.o[1]=tbf(a.y); pk.o[2]=tbf(a.z); pk.o[3]=tbf(a.w);
    pk.o[4]=tbf(b.x); pk.o[5]=tbf(b.y); pk.o[6]=tbf(b.z); pk.o[7]=tbf(b.w);
    *(uint4*)(xb + (size_t)row * D_MODEL + lane * 8) = pk.u;
    const float* wc = wcol + lane * 8;
    float s = a.x*wc[0]+a.y*wc[1]+a.z*wc[2]+a.w*wc[3]
            + b.x*wc[4]+b.y*wc[5]+b.z*wc[6]+b.w*wc[7];
    #pragma unroll
    for (int off = 32; off; off >>= 1) s += __shfl_xor(s, off);
    if (lane == 0) {
        float raw = s + dt_bias[0];
        dts[row] = raw > 20.f ? raw : log1pf(expf(raw));
    }
}

// ---------- batched NT GEMM, 128x128 tile, BK=64, global_load_lds + XOR swizzle ----------
// MODE 0: fp32 out.  MODE 1: bf16 out.
template<int MODE>
__global__ __launch_bounds__(256) void k_bgemm(
    const bf16* __restrict__ A, int lda, size_t sA,
    const bf16* __restrict__ Bt, int ldb, size_t sB,
    void* __restrict__ Cv, int ldc, size_t sC, int K)
{
    constexpr int BK = 64;
    __shared__ __align__(16) bf16 As[128][BK];
    __shared__ __align__(16) bf16 Bs[128][BK];
    const int tid = threadIdx.x, lane = tid & 63, wave = tid >> 6;
    const int wm = (wave & 1) * 64, wn = (wave >> 1) * 64;
    const int lr = lane & 15, quad = lane >> 4;
    const int rx = lr & 7;
    const size_t bm = (size_t)blockIdx.x * 128;
    const size_t bn = (size_t)blockIdx.y * 128;
    const size_t bi = blockIdx.z;
    A  += bi * sA;
    Bt += bi * sB;
    const int srow = lane >> 3;
    const int scol = (((lane & 7) ^ srow) << 3);

    f32x4 acc[4][4];
    #pragma unroll
    for (int i = 0; i < 4; ++i)
        #pragma unroll
        for (int j = 0; j < 4; ++j) acc[i][j] = (f32x4){0.f,0.f,0.f,0.f};

    for (int k0 = 0; k0 < K; k0 += BK) {
        __syncthreads();
        #pragma unroll
        for (int q = 0; q < 4; ++q) {
            int rg = wave * 32 + q * 8;
            gl2lds16(A  + (bm + rg + srow) * lda + k0 + scol, &As[rg][0]);
            gl2lds16(Bt + (bn + rg + srow) * ldb + k0 + scol, &Bs[rg][0]);
        }
        __syncthreads();
        #pragma unroll
        for (int ks = 0; ks < BK; ks += 32) {
            const int off = ((((ks >> 3) + quad) ^ rx) << 3);
            short8 af[4], bg[4];
            #pragma unroll
            for (int i = 0; i < 4; ++i)
                af[i] = *(const short8*)(&As[wm + i*16 + lr][off]);
            #pragma unroll
            for (int j = 0; j < 4; ++j)
                bg[j] = *(const short8*)(&Bs[wn + j*16 + lr][off]);
            #pragma unroll
            for (int i = 0; i < 4; ++i)
                #pragma unroll
                for (int j = 0; j < 4; ++j)
                    acc[i][j] = __builtin_amdgcn_mfma_f32_16x16x32_bf16(af[i], bg[j], acc[i][j], 0,0,0);
        }
    }
    #pragma unroll
    for (int i = 0; i < 4; ++i)
        #pragma unroll
        for (int j = 0; j < 4; ++j)
            #pragma unroll
            for (int r = 0; r < 4; ++r) {
                size_t row = bm + wm + i*16 + quad*4 + r;
                size_t col = bn + wn + j*16 + lr;
                float v = acc[i][j][r];
                if (MODE == 0) ((float*)Cv + bi*sC)[row * ldc + col] = v;
                else           ((bf16*)Cv + bi*sC)[row * ldc + col] = tbf(v);
            }
}

// ---------- GEMM1 with split output: cols<1024 -> zb, else xBCin ----------
__global__ __launch_bounds__(256) void k_gemm_in(
    const bf16* __restrict__ A, const bf16* __restrict__ Bt,
    bf16* __restrict__ zb, bf16* __restrict__ xBCin, int K)
{
    constexpr int BK = 64;
    __shared__ __align__(16) bf16 As[128][BK];
    __shared__ __align__(16) bf16 Bs[128][BK];
    const int tid = threadIdx.x, lane = tid & 63, wave = tid >> 6;
    const int wm = (wave & 1) * 64, wn = (wave >> 1) * 64;
    const int lr = lane & 15, quad = lane >> 4;
    const int rx = lr & 7;
    const size_t bm = (size_t)blockIdx.x * 128;
    const int bn = blockIdx.y * 128;
    const int srow = lane >> 3;
    const int scol = (((lane & 7) ^ srow) << 3);

    f32x4 acc[4][4];
    #pragma unroll
    for (int i = 0; i < 4; ++i)
        #pragma unroll
        for (int j = 0; j < 4; ++j) acc[i][j] = (f32x4){0.f,0.f,0.f,0.f};

    for (int k0 = 0; k0 < K; k0 += BK) {
        __syncthreads();
        #pragma unroll
        for (int q = 0; q < 4; ++q) {
            int rg = wave * 32 + q * 8;
            gl2lds16(A  + (bm + rg + srow) * K + k0 + scol, &As[rg][0]);
            gl2lds16(Bt + ((size_t)bn + rg + srow) * K + k0 + scol, &Bs[rg][0]);
        }
        __syncthreads();
        #pragma unroll
        for (int ks = 0; ks < BK; ks += 32) {
            const int off = ((((ks >> 3) + quad) ^ rx) << 3);
            short8 af[4], bg[4];
            #pragma unroll
            for (int i = 0; i < 4; ++i)
                af[i] = *(const short8*)(&As[wm + i*16 + lr][off]);
            #pragma unroll
            for (int j = 0; j < 4; ++j)
                bg[j] = *(const short8*)(&Bs[wn + j*16 + lr][off]);
            #pragma unroll
            for (int i = 0; i < 4; ++i)
                #pragma unroll
                for (int j = 0; j < 4; ++j)
                    acc[i][j] = __builtin_amdgcn_mfma_f32_16x16x32_bf16(af[i], bg[j], acc[i][j], 0,0,0);
        }
    }
    #pragma unroll
    for (int i = 0; i < 4; ++i)
        #pragma unroll
        for (int j = 0; j < 4; ++j)
            #pragma unroll
            for (int r = 0; r < 4; ++r) {
                size_t row = bm + wm + i*16 + quad*4 + r;
                int col = bn + wn + j*16 + lr;
                float v = acc[i][j][r];
                if (col < D_INNER) zb[row * D_INNER + col] = tbf(v);
                else xBCin[row * CONV_DIM + (col - D_INNER)] = tbf(v);
            }
}

// ---------- per-chunk cumsum of a_t = A*dt, decay factors ----------
__global__ void k_prep(const float* __restrict__ dts, const float* __restrict__ A_log,
                       float* __restrict__ svec, float* __restrict__ wvec,
                       float* __restrict__ esvec, float* __restrict__ Pc)
{
    int chunk = blockIdx.x, t = threadIdx.x;  // 128 threads
    int row = chunk * CHUNK + t;
    float A = -expf(A_log[0]);
    __shared__ float sh[CHUNK];
    sh[t] = A * dts[row];
    __syncthreads();
    for (int off = 1; off < CHUNK; off <<= 1) {
        float v = (t >= off) ? sh[t - off] : 0.f;
        __syncthreads();
        sh[t] += v;
        __syncthreads();
    }
    float s = sh[t], sL = sh[CHUNK - 1];
    svec[row]  = s;
    wvec[row]  = expf(sL - s) * dts[row];
    esvec[row] = expf(s);
    if (t == CHUNK - 1) Pc[chunk] = expf(sL);
}

// ---------- fused conv(B,C) + G = C@B^T + Sm epilogue + Bw/Cs builds ----------
// grid NCHUNK, 256 threads. LDS ~105 KB.
__global__ __launch_bounds__(256) void k_ssd_bc(
    const bf16* __restrict__ xBCin, const float* __restrict__ conv_w,
    const float* __restrict__ conv_b, const float* __restrict__ wvec,
    const float* __restrict__ esvec, const float* __restrict__ svec,
    const float* __restrict__ dts, const float* __restrict__ Dp,
    bf16* __restrict__ Bw, bf16* __restrict__ A2)
{
    __shared__ __align__(16) bf16 Ls[131][128];
    __shared__ __align__(16) bf16 Bts[128][136];
    __shared__ __align__(16) bf16 Cts[128][136];
    __shared__ float sv_s[128], dt_s[128], wv_s[128], es_s[128];
    const int chunk = blockIdx.x;
    const int tid = threadIdx.x;
    const bool first = (chunk % CPB) == 0;
    const size_t rowbase = (size_t)chunk * CHUNK;
    if (tid < 128) {
        sv_s[tid] = svec[rowbase + tid];
        dt_s[tid] = dts[rowbase + tid];
        wv_s[tid] = wvec[rowbase + tid];
        es_s[tid] = esvec[rowbase + tid];
    }
    const int ch  = tid & 127;
    const int seg = tid >> 7;   // t-half

    #pragma unroll
    for (int phase = 0; phase < 2; ++phase) {
        const int coff = D_INNER + phase * 128;   // B then C channel base
        __syncthreads();   // Ls safe to (re)fill; also covers sv_s et al on phase 0
        for (int i = tid; i < 131 * 16; i += 256) {
            int r = i >> 4, cg = (i & 15) << 3;
            uint4 v = (uint4){0,0,0,0};
            if (!(first && r < 3))
                v = *(const uint4*)(xBCin + (rowbase + r - 3) * CONV_DIM + coff + cg);
            *(uint4*)(&Ls[r][cg]) = v;
        }
        __syncthreads();
        float4 w = *(const float4*)(conv_w + (coff + ch) * 4);
        float bias = conv_b[coff + ch];
        float xv[11];
        #pragma unroll
        for (int i = 0; i < 3; ++i) xv[i + 8] = fbf(Ls[seg * 64 + i][ch]);
        for (int v = 0; v < 8; ++v) {
            int t0 = seg * 64 + v * 8;
            xv[0]=xv[8]; xv[1]=xv[9]; xv[2]=xv[10];
            #pragma unroll
            for (int i = 3; i < 11; ++i) xv[i] = fbf(Ls[t0 + i][ch]);
            float o[8];
            #pragma unroll
            for (int j = 0; j < 8; ++j) {
                float a = bias + w.x*xv[j] + w.y*xv[j+1] + w.z*xv[j+2] + w.w*xv[j+3];
                o[j] = a / (1.f + expf(-a));
            }
            if (phase == 0) {
                union { bf16 ob[8]; uint4 u; } pk;
                #pragma unroll
                for (int j = 0; j < 8; ++j) {
                    Bts[t0 + j][ch] = tbf(o[j]);
                    pk.ob[j] = tbf(o[j] * wv_s[t0 + j]);
                }
                *(uint4*)(Bw + (size_t)chunk*(D_STATE*CHUNK) + (size_t)ch*CHUNK + t0) = pk.u;
            } else {
                #pragma unroll
                for (int j = 0; j < 8; ++j) {
                    Cts[t0 + j][ch] = tbf(o[j]);
                    A2[(size_t)chunk*(CHUNK*256) + (size_t)(t0+j)*256 + 128 + ch] =
                        tbf(o[j] * es_s[t0 + j]);
                }
            }
        }
    }
    __syncthreads();
    // G = C @ B^T from LDS (K=128), Sm epilogue -> A2[:, 0:128]
    const int lane = tid & 63, wave = tid >> 6;
    const int wm = (wave & 1) * 64, wn = (wave >> 1) * 64;
    const int lr = lane & 15, quad = lane >> 4;
    f32x4 acc[4][4];
    #pragma unroll
    for (int i = 0; i < 4; ++i)
        #pragma unroll
        for (int j = 0; j < 4; ++j) acc[i][j] = (f32x4){0.f,0.f,0.f,0.f};
    #pragma unroll
    for (int ks = 0; ks < 128; ks += 32) {
        short8 af[4], bg[4];
        #pragma unroll
        for (int i = 0; i < 4; ++i)
            af[i] = *(const short8*)(&Cts[wm + i*16 + lr][ks + quad*8]);
        #pragma unroll
        for (int j = 0; j < 4; ++j)
            bg[j] = *(const short8*)(&Bts[wn + j*16 + lr][ks + quad*8]);
        #pragma unroll
        for (int i = 0; i < 4; ++i)
            #pragma unroll
            for (int j = 0; j < 4; ++j)
                acc[i][j] = __builtin_amdgcn_mfma_f32_16x16x32_bf16(af[i], bg[j], acc[i][j], 0,0,0);
    }
    const float D0 = Dp[0];
    #pragma unroll
    for (int i = 0; i < 4; ++i)
        #pragma unroll
        for (int j = 0; j < 4; ++j)
            #pragma unroll
            for (int r = 0; r < 4; ++r) {
                int t = wm + i*16 + quad*4 + r;
                int u = wn + j*16 + lr;
                float o = 0.f;
                if (u <= t) {
                    o = acc[i][j][r] * expf(sv_s[t] - sv_s[u]) * dt_s[u];
                    if (u == t) o += D0;
                }
                A2[(size_t)chunk*(CHUNK*256) + (size_t)t*256 + u] = tbf(o);
            }
}

// ---------- fused conv(x) -> Xt (B2 + LDS) + dH = Xt @ Bw^T ----------
// grid (8, NCHUNK), 256 threads. LDS ~103 KB.
__global__ __launch_bounds__(256) void k_conv_xdh(
    const bf16* __restrict__ xBCin, const float* __restrict__ conv_w,
    const float* __restrict__ conv_b, const bf16* __restrict__ Bw,
    bf16* __restrict__ B2, bf16* __restrict__ dH)
{
    __shared__ __align__(16) bf16 Ls[131][128];
    __shared__ __align__(16) bf16 Xs[128][136];   // [p][t]
    __shared__ __align__(16) bf16 Bws[128][136];  // [n][t]
    const int chunk = blockIdx.y;
    const int p0 = blockIdx.x * 128;
    const int tid = threadIdx.x;
    const bool first = (chunk % CPB) == 0;
    const size_t rowbase = (size_t)chunk * CHUNK;
    for (int i = tid; i < 131 * 16; i += 256) {
        int r = i >> 4, cg = (i & 15) << 3;
        uint4 v = (uint4){0,0,0,0};
        if (!(first && r < 3))
            v = *(const uint4*)(xBCin + (rowbase + r - 3) * CONV_DIM + p0 + cg);
        *(uint4*)(&Ls[r][cg]) = v;
    }
    for (int i = tid; i < 128 * 16; i += 256) {
        int nr = i >> 4, cg = (i & 15) << 3;
        *(uint4*)(&Bws[nr][cg]) =
            *(const uint4*)(Bw + (size_t)chunk*(D_STATE*CHUNK) + (size_t)nr*CHUNK + cg);
    }
    __syncthreads();
    const int p = tid & 127;
    const int half = tid >> 7;
    const int ch = p0 + p;
    float4 w = *(const float4*)(conv_w + ch * 4);
    float bias = conv_b[ch];
    bf16* outrow = B2 + (size_t)chunk * (D_INNER * 256) + (size_t)ch * 256;
    float xv[11];
    #pragma unroll
    for (int i = 0; i < 3; ++i) xv[i + 8] = fbf(Ls[half * 64 + i][p]);
    for (int v = 0; v < 8; ++v) {
        int t0 = half * 64 + v * 8;
        xv[0]=xv[8]; xv[1]=xv[9]; xv[2]=xv[10];
        #pragma unroll
        for (int i = 3; i < 11; ++i) xv[i] = fbf(Ls[t0 + i][p]);
        union { bf16 o[8]; uint4 u; } pk;
        #pragma unroll
        for (int j = 0; j < 8; ++j) {
            float a = bias + w.x*xv[j] + w.y*xv[j+1] + w.z*xv[j+2] + w.w*xv[j+3];
            pk.o[j] = tbf(a / (1.f + expf(-a)));
        }
        *(uint4*)(outrow + t0) = pk.u;
        *(uint4*)(&Xs[p][t0]) = pk.u;
    }
    __syncthreads();
    // dH[p][n] = sum_t Xs[p][t] * Bws[n][t]  (K=128)
    const int lane = tid & 63, wave = tid >> 6;
    const int wm = (wave & 1) * 64, wn = (wave >> 1) * 64;
    const int lr = lane & 15, quad = lane >> 4;
    f32x4 acc[4][4];
    #pragma unroll
    for (int i = 0; i < 4; ++i)
        #pragma unroll
        for (int j = 0; j < 4; ++j) acc[i][j] = (f32x4){0.f,0.f,0.f,0.f};
    #pragma unroll
    for (int ks = 0; ks < 128; ks += 32) {
        short8 af[4], bg[4];
        #pragma unroll
        for (int i = 0; i < 4; ++i)
            af[i] = *(const short8*)(&Xs[wm + i*16 + lr][ks + quad*8]);
        #pragma unroll
        for (int j = 0; j < 4; ++j)
            bg[j] = *(const short8*)(&Bws[wn + j*16 + lr][ks + quad*8]);
        #pragma unroll
        for (int i = 0; i < 4; ++i)
            #pragma unroll
            for (int j = 0; j < 4; ++j)
                acc[i][j] = __builtin_amdgcn_mfma_f32_16x16x32_bf16(af[i], bg[j], acc[i][j], 0,0,0);
    }
    #pragma unroll
    for (int i = 0; i < 4; ++i)
        #pragma unroll
        for (int j = 0; j < 4; ++j)
            #pragma unroll
            for (int r = 0; r < 4; ++r) {
                int pr = p0 + wm + i*16 + quad*4 + r;
                int n  = wn + j*16 + lr;
                dH[(size_t)chunk*(D_INNER*D_STATE) + (size_t)pr*D_STATE + n] = tbf(acc[i][j][r]);
            }
}

// ---------- sequential carry over 16 chunks/batch, prefetched ----------
__global__ void k_carry(const bf16* __restrict__ dH, const float* __restrict__ Pc,
                        bf16* __restrict__ B2)
{
    int idx = blockIdx.x * 256 + threadIdx.x;   // p*128+n
    int b = blockIdx.y;
    int p = idx >> 7, n = idx & 127;
    float v[CPB], pc[CPB];
    #pragma unroll
    for (int c = 0; c < CPB; ++c)
        v[c] = fbf(dH[(size_t)(b*CPB + c) * (D_INNER*D_STATE) + idx]);
    #pragma unroll
    for (int c = 0; c < CPB; ++c) pc[c] = Pc[b*CPB + c];
    float h = 0.f;
    #pragma unroll
    for (int c = 0; c < CPB; ++c) {
        int bi = b * CPB + c;
        B2[(size_t)bi * (D_INNER*256) + (size_t)p * 256 + 128 + n] = tbf(h);
        h = pc[c] * h + v[c];
    }
}

// ---------- gate (silu(z)) + RMSNorm, wave-per-row, in-place on bf16 y ----------
__global__ __launch_bounds__(256) void k_gate_norm(
    bf16* __restrict__ y, const bf16* __restrict__ zb,
    const float* __restrict__ norm_w)
{
    int row  = blockIdx.x * 4 + (threadIdx.x >> 6);
    int lane = threadIdx.x & 63;
    bf16* yr = y + (size_t)row * D_INNER;
    const bf16* zr = zb + (size_t)row * D_INNER;
    const int c0 = lane * 8, c1 = 512 + lane * 8;
    union { bf16 b[8]; uint4 u; } y0, y1, z0, z1;
    y0.u = *(const uint4*)(yr + c0); y1.u = *(const uint4*)(yr + c1);
    z0.u = *(const uint4*)(zr + c0); z1.u = *(const uint4*)(zr + c1);
    float v[16], ss = 0.f;
    #pragma unroll
    for (int j = 0; j < 8; ++j) {
        float z = fbf(z0.b[j]);
        v[j] = fbf(y0.b[j]) * z / (1.f + expf(-z));
        ss += v[j] * v[j];
    }
    #pragma unroll
    for (int j = 0; j < 8; ++j) {
        float z = fbf(z1.b[j]);
        v[8+j] = fbf(y1.b[j]) * z / (1.f + expf(-z));
        ss += v[8+j] * v[8+j];
    }
    #pragma unroll
    for (int off = 32; off; off >>= 1) ss += __shfl_xor(ss, off);
    float scale = rsqrtf(ss * (1.f / D_INNER) + EPS_RMS);
    union { bf16 b[8]; uint4 u; } p0, p1;
    #pragma unroll
    for (int j = 0; j < 8; ++j) p0.b[j] = tbf(v[j]   * scale * norm_w[c0 + j]);
    #pragma unroll
    for (int j = 0; j < 8; ++j) p1.b[j] = tbf(v[8+j] * scale * norm_w[c1 + j]);
    *(uint4*)(yr + c0) = p0.u;
    *(uint4*)(yr + c1) = p1.u;
}

extern "C" void kernel_launch(void* const* d_in, const int* in_sizes, int n_in,
                              void* d_out, int out_size, void* d_ws, size_t ws_size,
                              hipStream_t stream)
{
    const float* x       = (const float*)d_in[0];
    const float* rnn     = (const float*)d_in[1];
    const float* W_in    = (const float*)d_in[2];
    const float* conv_w  = (const float*)d_in[3];
    const float* conv_b  = (const float*)d_in[4];
    const float* dt_bias = (const float*)d_in[5];
    const float* A_log   = (const float*)d_in[6];
    const float* Dp      = (const float*)d_in[7];
    const float* norm_w  = (const float*)d_in[8];
    const float* W_out   = (const float*)d_in[9];
    float* out = (float*)d_out;

    char* ws = (char*)d_ws;
    size_t off = 0;
    auto alloc = [&](size_t bytes) { void* p = ws + off; off += (bytes + 255) & ~255ULL; return p; };

    // ---- persistent ----
    bf16*  W_inbT  = (bf16*) alloc((size_t)NPROJ * D_MODEL * 2);        // 2.36M
    bf16*  W_outbT = (bf16*) alloc((size_t)D_MODEL * D_INNER * 2);      // 1.05M
    float* dts     = (float*)alloc((size_t)NROWS * 4);
    float* svec    = (float*)alloc((size_t)NROWS * 4);
    float* wvec    = (float*)alloc((size_t)NROWS * 4);
    float* esvec   = (float*)alloc((size_t)NROWS * 4);
    float* Pc      = (float*)alloc((size_t)NCHUNK * 4);
    bf16*  zb      = (bf16*) alloc((size_t)NROWS * D_INNER * 2);        // 33.5M
    bf16*  A2      = (bf16*) alloc((size_t)NCHUNK * CHUNK * 256 * 2);   // 8.4M  [Sm | Cs]
    bf16*  B2      = (bf16*) alloc((size_t)NCHUNK * D_INNER * 256 * 2); // 67.1M [Xt | Hprev]
    bf16*  Bw      = (bf16*) alloc((size_t)NCHUNK * D_STATE * CHUNK * 2); // 4.2M
    // ---- aliased region A (50.3M): xb[0:16.8]+dH[16.8:50.3], later ybf[0:33.5] ----
    char* RA = (char*)alloc((size_t)NROWS * D_MODEL * 2 + (size_t)NROWS * D_INNER * 2);
    bf16*  xb   = (bf16*)RA;                                   // [dtcvt -> GEMM1]
    bf16*  dH   = (bf16*)(RA + (size_t)NROWS * D_MODEL * 2);   // [conv_xdh -> carry]
    bf16*  ybf  = (bf16*)RA;                                   // [Y-GEMM -> norm -> GEMM2]
    // ---- region B: xBCin [GEMM1 -> convs] ----
    bf16*  xBCin = (bf16*)alloc((size_t)NROWS * CONV_DIM * 2); // 41.9M
    // total ~200 MB

    // 1. fused convert + dt GEMV; weight transposes; cumsum prep
    k_dtcvt<<<NROWS / 4, 256, 0, stream>>>(x, W_in, dt_bias, xb, dts);
    k_transpose_cvt<<<dim3(D_MODEL/32, NPROJ/32), dim3(32, 8), 0, stream>>>(
        W_in, W_inbT, NPROJ, D_MODEL, D_IN_PROJ);
    k_transpose_cvt<<<dim3(D_INNER/32, D_MODEL/32), dim3(32, 8), 0, stream>>>(
        W_out, W_outbT, D_MODEL, D_INNER, D_MODEL);
    k_prep<<<NCHUNK, CHUNK, 0, stream>>>(dts, A_log, svec, wvec, esvec, Pc);

    // 2. in-projection GEMM with split output
    k_gemm_in<<<dim3(NROWS/128, NPROJ/128), 256, 0, stream>>>(xb, W_inbT, zb, xBCin, D_MODEL);

    // 3. fused conv(B,C) + G-GEMM + Sm -> A2, Bw
    k_ssd_bc<<<NCHUNK, 256, 0, stream>>>(xBCin, conv_w, conv_b, wvec, esvec,
                                         svec, dts, Dp, Bw, A2);

    // 4. fused conv(x) -> Xt(B2) + dH-GEMM
    k_conv_xdh<<<dim3(8, NCHUNK), 256, 0, stream>>>(xBCin, conv_w, conv_b, Bw, B2, dH);

    // 5. carry states -> Hprev region of B2
    k_carry<<<dim3(D_INNER*D_STATE/256, BATCH), 256, 0, stream>>>(dH, Pc, B2);

    // 6. Y = [Sm|Cs] @ [Xt|Hprev]^T  (K=256) -> ybf (bf16)
    k_bgemm<1><<<dim3(1, D_INNER/128, NCHUNK), 256, 0, stream>>>(
        A2, 256, (size_t)CHUNK*256,
        B2, 256, (size_t)D_INNER*256,
        ybf, D_INNER, (size_t)CHUNK*D_INNER, 256);

    // 7. gate + RMSNorm in-place on ybf (wave per row)
    k_gate_norm<<<NROWS / 4, 256, 0, stream>>>(ybf, zb, norm_w);

    // 8. out-projection GEMM -> d_out
    k_bgemm<0><<<dim3(NROWS/128, D_MODEL/128, 1), 256, 0, stream>>>(
        ybf, D_INNER, 0, W_outbT, D_INNER, 0, out, D_MODEL, 0, D_INNER);

    // 9. rnn_state passthrough
    hipMemcpyAsync(out + (size_t)NROWS * D_MODEL, rnn,
                   (size_t)BATCH * D_MODEL * sizeof(float),
                   hipMemcpyDeviceToDevice, stream);
}

// Round 7
// 321.090 us; speedup vs baseline: 1.1298x; 1.0063x over previous
//
#include <hip/hip_runtime.h>
#include <hip/hip_bf16.h>
#include <math.h>

#define D_MODEL 512
#define D_INNER 1024
#define D_STATE 128
#define CONV_DIM (D_INNER + 2*D_STATE)        // 1280
#define D_IN_PROJ (2*D_INNER + 2*D_STATE + 1) // 2305
#define NPROJ 2304                            // z + xBC cols (dt col via GEMV)
#define BATCH 8
#define SEQ 2048
#define NROWS (BATCH*SEQ)                     // 16384
#define CHUNK 128
#define NCHUNK (NROWS/CHUNK)                  // 128 total (16 per batch)
#define CPB (SEQ/CHUNK)                       // 16 chunks per batch
#define EPS_RMS 1e-5f

typedef __hip_bfloat16 bf16;
typedef __attribute__((ext_vector_type(8))) short short8;
typedef __attribute__((ext_vector_type(4))) float f32x4;

__device__ __forceinline__ float fbf(bf16 v) { return __bfloat162float(v); }
__device__ __forceinline__ bf16 tbf(float v) { return __float2bfloat16(v); }

// async global->LDS, 16B per lane; LDS dest is wave-uniform base + lane*16
__device__ __forceinline__ void gl2lds16(const bf16* g, bf16* l) {
    __builtin_amdgcn_global_load_lds(
        (const __attribute__((address_space(1))) unsigned int*)g,
        (__attribute__((address_space(3))) unsigned int*)l, 16, 0, 0);
}

// ---------- transpose + convert (+optional src-row scale): dst[r][c] = bf16(src[c][r]*s[c]) ----------
__global__ void k_transpose_cvt(const float* __restrict__ src, bf16* __restrict__ dst,
                                int R, int C, int sstride, const float* __restrict__ scale) {
    __shared__ float tile[32][33];
    int c0 = blockIdx.x * 32, r0 = blockIdx.y * 32;
    int tx = threadIdx.x, ty = threadIdx.y;
    #pragma unroll
    for (int i = 0; i < 32; i += 8) {
        float s = scale ? scale[c0 + ty + i] : 1.f;
        tile[ty + i][tx] = src[(size_t)(c0 + ty + i) * sstride + (r0 + tx)] * s;
    }
    __syncthreads();
    #pragma unroll
    for (int i = 0; i < 32; i += 8)
        dst[(size_t)(r0 + ty + i) * C + (c0 + tx)] = tbf(tile[tx][ty + i]);
}

// ---------- fused x->bf16 convert + dt GEMV + softplus ----------
__global__ __launch_bounds__(256) void k_dtcvt(
    const float* __restrict__ x, const float* __restrict__ W_in,
    const float* __restrict__ dt_bias,
    bf16* __restrict__ xb, float* __restrict__ dts)
{
    __shared__ float wcol[D_MODEL];
    int tid = threadIdx.x;
    wcol[tid]       = W_in[(size_t)tid * D_IN_PROJ + 2304];
    wcol[tid + 256] = W_in[(size_t)(tid + 256) * D_IN_PROJ + 2304];
    __syncthreads();
    int row  = blockIdx.x * 4 + (tid >> 6);
    int lane = tid & 63;
    const float* xr = x + (size_t)row * D_MODEL;
    float4 a = *(const float4*)(xr + lane * 8);
    float4 b = *(const float4*)(xr + lane * 8 + 4);
    union { bf16 o[8]; uint4 u; } pk;
    pk.o[0]=tbf(a.x); pk.o[1]=tbf(a.y); pk.o[2]=tbf(a.z); pk.o[3]=tbf(a.w);
    pk.o[4]=tbf(b.x); pk.o[5]=tbf(b.y); pk.o[6]=tbf(b.z); pk.o[7]=tbf(b.w);
    *(uint4*)(xb + (size_t)row * D_MODEL + lane * 8) = pk.u;
    const float* wc = wcol + lane * 8;
    float s = a.x*wc[0]+a.y*wc[1]+a.z*wc[2]+a.w*wc[3]
            + b.x*wc[4]+b.y*wc[5]+b.z*wc[6]+b.w*wc[7];
    #pragma unroll
    for (int off = 32; off; off >>= 1) s += __shfl_xor(s, off);
    if (lane == 0) {
        float raw = s + dt_bias[0];
        dts[row] = raw > 20.f ? raw : log1pf(expf(raw));
    }
}

// ---------- batched NT GEMM, 128x128 tile, BK=64, global_load_lds + XOR swizzle ----------
// MODE 0: fp32 out.  MODE 1: bf16 out.
// MODE 2: Y-epilogue — gate with silu(zg), store bf16, atomicAdd per-row sumsq into ssq.
// MODE 3: out fp32 scaled by rsqrt(ssq[row]/D_INNER + eps) (RMSNorm post-scale).
template<int MODE>
__global__ __launch_bounds__(256) void k_bgemm(
    const bf16* __restrict__ A, int lda, size_t sA,
    const bf16* __restrict__ Bt, int ldb, size_t sB,
    void* __restrict__ Cv, int ldc, size_t sC, int K,
    const bf16* __restrict__ zg, float* __restrict__ ssq)
{
    constexpr int BK = 64;
    __shared__ __align__(16) bf16 As[128][BK];
    __shared__ __align__(16) bf16 Bs[128][BK];
    const int tid = threadIdx.x, lane = tid & 63, wave = tid >> 6;
    const int wm = (wave & 1) * 64, wn = (wave >> 1) * 64;
    const int lr = lane & 15, quad = lane >> 4;
    const int rx = lr & 7;
    const size_t bm = (size_t)blockIdx.x * 128;
    const size_t bn = (size_t)blockIdx.y * 128;
    const size_t bi = blockIdx.z;
    A  += bi * sA;
    Bt += bi * sB;
    const int srow = lane >> 3;
    const int scol = (((lane & 7) ^ srow) << 3);

    f32x4 acc[4][4];
    #pragma unroll
    for (int i = 0; i < 4; ++i)
        #pragma unroll
        for (int j = 0; j < 4; ++j) acc[i][j] = (f32x4){0.f,0.f,0.f,0.f};

    for (int k0 = 0; k0 < K; k0 += BK) {
        __syncthreads();
        #pragma unroll
        for (int q = 0; q < 4; ++q) {
            int rg = wave * 32 + q * 8;
            gl2lds16(A  + (bm + rg + srow) * lda + k0 + scol, &As[rg][0]);
            gl2lds16(Bt + (bn + rg + srow) * ldb + k0 + scol, &Bs[rg][0]);
        }
        __syncthreads();
        #pragma unroll
        for (int ks = 0; ks < BK; ks += 32) {
            const int off = ((((ks >> 3) + quad) ^ rx) << 3);
            short8 af[4], bg[4];
            #pragma unroll
            for (int i = 0; i < 4; ++i)
                af[i] = *(const short8*)(&As[wm + i*16 + lr][off]);
            #pragma unroll
            for (int j = 0; j < 4; ++j)
                bg[j] = *(const short8*)(&Bs[wn + j*16 + lr][off]);
            #pragma unroll
            for (int i = 0; i < 4; ++i)
                #pragma unroll
                for (int j = 0; j < 4; ++j)
                    acc[i][j] = __builtin_amdgcn_mfma_f32_16x16x32_bf16(af[i], bg[j], acc[i][j], 0,0,0);
        }
    }
    if (MODE <= 1) {
        #pragma unroll
        for (int i = 0; i < 4; ++i)
            #pragma unroll
            for (int j = 0; j < 4; ++j)
                #pragma unroll
                for (int r = 0; r < 4; ++r) {
                    size_t row = bm + wm + i*16 + quad*4 + r;
                    size_t col = bn + wn + j*16 + lr;
                    float v = acc[i][j][r];
                    if (MODE == 0) ((float*)Cv + bi*sC)[row * ldc + col] = v;
                    else           ((bf16*)Cv + bi*sC)[row * ldc + col] = tbf(v);
                }
    } else if (MODE == 2) {
        const size_t tokbase = bi * CHUNK;
        float srw[4][4];
        #pragma unroll
        for (int i = 0; i < 4; ++i)
            #pragma unroll
            for (int r = 0; r < 4; ++r) srw[i][r] = 0.f;
        #pragma unroll
        for (int i = 0; i < 4; ++i)
            #pragma unroll
            for (int j = 0; j < 4; ++j)
                #pragma unroll
                for (int r = 0; r < 4; ++r) {
                    size_t row = bm + wm + i*16 + quad*4 + r;
                    size_t col = bn + wn + j*16 + lr;
                    float z = fbf(zg[(tokbase + row) * D_INNER + col]);
                    float g = acc[i][j][r] * z / (1.f + expf(-z));
                    ((bf16*)Cv + bi*sC)[row * ldc + col] = tbf(g);
                    srw[i][r] += g * g;
                }
        #pragma unroll
        for (int i = 0; i < 4; ++i)
            #pragma unroll
            for (int r = 0; r < 4; ++r) {
                float s = srw[i][r];
                s += __shfl_xor(s, 1);
                s += __shfl_xor(s, 2);
                s += __shfl_xor(s, 4);
                s += __shfl_xor(s, 8);
                if (lr == 0)
                    atomicAdd(ssq + tokbase + bm + wm + i*16 + quad*4 + r, s);
            }
    } else {  // MODE 3
        #pragma unroll
        for (int i = 0; i < 4; ++i)
            #pragma unroll
            for (int r = 0; r < 4; ++r) {
                size_t row = bm + wm + i*16 + quad*4 + r;
                float sc = rsqrtf(ssq[row] * (1.f / D_INNER) + EPS_RMS);
                #pragma unroll
                for (int j = 0; j < 4; ++j) {
                    size_t col = bn + wn + j*16 + lr;
                    ((float*)Cv + bi*sC)[row * ldc + col] = acc[i][j][r] * sc;
                }
            }
    }
}

// ---------- GEMM1 with split output: cols<1024 -> zb, else xBCin ----------
__global__ __launch_bounds__(256) void k_gemm_in(
    const bf16* __restrict__ A, const bf16* __restrict__ Bt,
    bf16* __restrict__ zb, bf16* __restrict__ xBCin, int K)
{
    constexpr int BK = 64;
    __shared__ __align__(16) bf16 As[128][BK];
    __shared__ __align__(16) bf16 Bs[128][BK];
    const int tid = threadIdx.x, lane = tid & 63, wave = tid >> 6;
    const int wm = (wave & 1) * 64, wn = (wave >> 1) * 64;
    const int lr = lane & 15, quad = lane >> 4;
    const int rx = lr & 7;
    const size_t bm = (size_t)blockIdx.x * 128;
    const int bn = blockIdx.y * 128;
    const int srow = lane >> 3;
    const int scol = (((lane & 7) ^ srow) << 3);

    f32x4 acc[4][4];
    #pragma unroll
    for (int i = 0; i < 4; ++i)
        #pragma unroll
        for (int j = 0; j < 4; ++j) acc[i][j] = (f32x4){0.f,0.f,0.f,0.f};

    for (int k0 = 0; k0 < K; k0 += BK) {
        __syncthreads();
        #pragma unroll
        for (int q = 0; q < 4; ++q) {
            int rg = wave * 32 + q * 8;
            gl2lds16(A  + (bm + rg + srow) * K + k0 + scol, &As[rg][0]);
            gl2lds16(Bt + ((size_t)bn + rg + srow) * K + k0 + scol, &Bs[rg][0]);
        }
        __syncthreads();
        #pragma unroll
        for (int ks = 0; ks < BK; ks += 32) {
            const int off = ((((ks >> 3) + quad) ^ rx) << 3);
            short8 af[4], bg[4];
            #pragma unroll
            for (int i = 0; i < 4; ++i)
                af[i] = *(const short8*)(&As[wm + i*16 + lr][off]);
            #pragma unroll
            for (int j = 0; j < 4; ++j)
                bg[j] = *(const short8*)(&Bs[wn + j*16 + lr][off]);
            #pragma unroll
            for (int i = 0; i < 4; ++i)
                #pragma unroll
                for (int j = 0; j < 4; ++j)
                    acc[i][j] = __builtin_amdgcn_mfma_f32_16x16x32_bf16(af[i], bg[j], acc[i][j], 0,0,0);
        }
    }
    #pragma unroll
    for (int i = 0; i < 4; ++i)
        #pragma unroll
        for (int j = 0; j < 4; ++j)
            #pragma unroll
            for (int r = 0; r < 4; ++r) {
                size_t row = bm + wm + i*16 + quad*4 + r;
                int col = bn + wn + j*16 + lr;
                float v = acc[i][j][r];
                if (col < D_INNER) zb[row * D_INNER + col] = tbf(v);
                else xBCin[row * CONV_DIM + (col - D_INNER)] = tbf(v);
            }
}

// ---------- per-chunk cumsum of a_t = A*dt, decay factors ----------
__global__ void k_prep(const float* __restrict__ dts, const float* __restrict__ A_log,
                       float* __restrict__ svec, float* __restrict__ wvec,
                       float* __restrict__ esvec, float* __restrict__ Pc)
{
    int chunk = blockIdx.x, t = threadIdx.x;  // 128 threads
    int row = chunk * CHUNK + t;
    float A = -expf(A_log[0]);
    __shared__ float sh[CHUNK];
    sh[t] = A * dts[row];
    __syncthreads();
    for (int off = 1; off < CHUNK; off <<= 1) {
        float v = (t >= off) ? sh[t - off] : 0.f;
        __syncthreads();
        sh[t] += v;
        __syncthreads();
    }
    float s = sh[t], sL = sh[CHUNK - 1];
    svec[row]  = s;
    wvec[row]  = expf(sL - s) * dts[row];
    esvec[row] = expf(s);
    if (t == CHUNK - 1) Pc[chunk] = expf(sL);
}

// ---------- fused conv(B,C) + G = C@B^T + Sm epilogue + Bw/Cs builds ----------
// grid NCHUNK, 256 threads.
__global__ __launch_bounds__(256) void k_ssd_bc(
    const bf16* __restrict__ xBCin, const float* __restrict__ conv_w,
    const float* __restrict__ conv_b, const float* __restrict__ wvec,
    const float* __restrict__ esvec, const float* __restrict__ svec,
    const float* __restrict__ dts, const float* __restrict__ Dp,
    bf16* __restrict__ Bw, bf16* __restrict__ A2)
{
    __shared__ __align__(16) bf16 Ls[131][128];
    __shared__ __align__(16) bf16 Bts[128][136];
    __shared__ __align__(16) bf16 Cts[128][136];
    __shared__ float sv_s[128], dt_s[128], wv_s[128], es_s[128];
    const int chunk = blockIdx.x;
    const int tid = threadIdx.x;
    const bool first = (chunk % CPB) == 0;
    const size_t rowbase = (size_t)chunk * CHUNK;
    if (tid < 128) {
        sv_s[tid] = svec[rowbase + tid];
        dt_s[tid] = dts[rowbase + tid];
        wv_s[tid] = wvec[rowbase + tid];
        es_s[tid] = esvec[rowbase + tid];
    }
    const int ch  = tid & 127;
    const int seg = tid >> 7;   // t-half

    #pragma unroll
    for (int phase = 0; phase < 2; ++phase) {
        const int coff = D_INNER + phase * 128;   // B then C channel base
        __syncthreads();
        for (int i = tid; i < 131 * 16; i += 256) {
            int r = i >> 4, cg = (i & 15) << 3;
            uint4 v = (uint4){0,0,0,0};
            if (!(first && r < 3))
                v = *(const uint4*)(xBCin + (rowbase + r - 3) * CONV_DIM + coff + cg);
            *(uint4*)(&Ls[r][cg]) = v;
        }
        __syncthreads();
        float4 w = *(const float4*)(conv_w + (coff + ch) * 4);
        float bias = conv_b[coff + ch];
        float xv[11];
        #pragma unroll
        for (int i = 0; i < 3; ++i) xv[i + 8] = fbf(Ls[seg * 64 + i][ch]);
        for (int v = 0; v < 8; ++v) {
            int t0 = seg * 64 + v * 8;
            xv[0]=xv[8]; xv[1]=xv[9]; xv[2]=xv[10];
            #pragma unroll
            for (int i = 3; i < 11; ++i) xv[i] = fbf(Ls[t0 + i][ch]);
            float o[8];
            #pragma unroll
            for (int j = 0; j < 8; ++j) {
                float a = bias + w.x*xv[j] + w.y*xv[j+1] + w.z*xv[j+2] + w.w*xv[j+3];
                o[j] = a / (1.f + expf(-a));
            }
            if (phase == 0) {
                union { bf16 ob[8]; uint4 u; } pk;
                #pragma unroll
                for (int j = 0; j < 8; ++j) {
                    Bts[t0 + j][ch] = tbf(o[j]);
                    pk.ob[j] = tbf(o[j] * wv_s[t0 + j]);
                }
                *(uint4*)(Bw + (size_t)chunk*(D_STATE*CHUNK) + (size_t)ch*CHUNK + t0) = pk.u;
            } else {
                #pragma unroll
                for (int j = 0; j < 8; ++j) {
                    Cts[t0 + j][ch] = tbf(o[j]);
                    A2[(size_t)chunk*(CHUNK*256) + (size_t)(t0+j)*256 + 128 + ch] =
                        tbf(o[j] * es_s[t0 + j]);
                }
            }
        }
    }
    __syncthreads();
    // G = C @ B^T from LDS (K=128), Sm epilogue -> A2[:, 0:128]
    const int lane = tid & 63, wave = tid >> 6;
    const int wm = (wave & 1) * 64, wn = (wave >> 1) * 64;
    const int lr = lane & 15, quad = lane >> 4;
    f32x4 acc[4][4];
    #pragma unroll
    for (int i = 0; i < 4; ++i)
        #pragma unroll
        for (int j = 0; j < 4; ++j) acc[i][j] = (f32x4){0.f,0.f,0.f,0.f};
    #pragma unroll
    for (int ks = 0; ks < 128; ks += 32) {
        short8 af[4], bg[4];
        #pragma unroll
        for (int i = 0; i < 4; ++i)
            af[i] = *(const short8*)(&Cts[wm + i*16 + lr][ks + quad*8]);
        #pragma unroll
        for (int j = 0; j < 4; ++j)
            bg[j] = *(const short8*)(&Bts[wn + j*16 + lr][ks + quad*8]);
        #pragma unroll
        for (int i = 0; i < 4; ++i)
            #pragma unroll
            for (int j = 0; j < 4; ++j)
                acc[i][j] = __builtin_amdgcn_mfma_f32_16x16x32_bf16(af[i], bg[j], acc[i][j], 0,0,0);
    }
    const float D0 = Dp[0];
    #pragma unroll
    for (int i = 0; i < 4; ++i)
        #pragma unroll
        for (int j = 0; j < 4; ++j)
            #pragma unroll
            for (int r = 0; r < 4; ++r) {
                int t = wm + i*16 + quad*4 + r;
                int u = wn + j*16 + lr;
                float o = 0.f;
                if (u <= t) {
                    o = acc[i][j][r] * expf(sv_s[t] - sv_s[u]) * dt_s[u];
                    if (u == t) o += D0;
                }
                A2[(size_t)chunk*(CHUNK*256) + (size_t)t*256 + u] = tbf(o);
            }
}

// ---------- fused conv(x) -> Xt (B2 + LDS) + dH = Xt @ Bw^T (B direct from global) ----------
// grid (8, NCHUNK), 256 threads. LDS 68.3 KB -> 2 blocks/CU.
__global__ __launch_bounds__(256) void k_conv_xdh(
    const bf16* __restrict__ xBCin, const float* __restrict__ conv_w,
    const float* __restrict__ conv_b, const bf16* __restrict__ Bw,
    bf16* __restrict__ B2, bf16* __restrict__ dH)
{
    __shared__ __align__(16) bf16 Ls[131][128];
    __shared__ __align__(16) bf16 Xs[128][136];   // [p][t]
    const int chunk = blockIdx.y;
    const int p0 = blockIdx.x * 128;
    const int tid = threadIdx.x;
    const bool first = (chunk % CPB) == 0;
    const size_t rowbase = (size_t)chunk * CHUNK;
    for (int i = tid; i < 131 * 16; i += 256) {
        int r = i >> 4, cg = (i & 15) << 3;
        uint4 v = (uint4){0,0,0,0};
        if (!(first && r < 3))
            v = *(const uint4*)(xBCin + (rowbase + r - 3) * CONV_DIM + p0 + cg);
        *(uint4*)(&Ls[r][cg]) = v;
    }
    __syncthreads();
    const int p = tid & 127;
    const int half = tid >> 7;
    const int ch = p0 + p;
    float4 w = *(const float4*)(conv_w + ch * 4);
    float bias = conv_b[ch];
    bf16* outrow = B2 + (size_t)chunk * (D_INNER * 256) + (size_t)ch * 256;
    float xv[11];
    #pragma unroll
    for (int i = 0; i < 3; ++i) xv[i + 8] = fbf(Ls[half * 64 + i][p]);
    for (int v = 0; v < 8; ++v) {
        int t0 = half * 64 + v * 8;
        xv[0]=xv[8]; xv[1]=xv[9]; xv[2]=xv[10];
        #pragma unroll
        for (int i = 3; i < 11; ++i) xv[i] = fbf(Ls[t0 + i][p]);
        union { bf16 o[8]; uint4 u; } pk;
        #pragma unroll
        for (int j = 0; j < 8; ++j) {
            float a = bias + w.x*xv[j] + w.y*xv[j+1] + w.z*xv[j+2] + w.w*xv[j+3];
            pk.o[j] = tbf(a / (1.f + expf(-a)));
        }
        *(uint4*)(outrow + t0) = pk.u;
        *(uint4*)(&Xs[p][t0]) = pk.u;
    }
    __syncthreads();
    // dH[p][n] = sum_t Xs[p][t] * Bw[n][t]  (K=128; B-frags straight from global)
    const int lane = tid & 63, wave = tid >> 6;
    const int wm = (wave & 1) * 64, wn = (wave >> 1) * 64;
    const int lr = lane & 15, quad = lane >> 4;
    const bf16* bwc = Bw + (size_t)chunk * (D_STATE * CHUNK);
    f32x4 acc[4][4];
    #pragma unroll
    for (int i = 0; i < 4; ++i)
        #pragma unroll
        for (int j = 0; j < 4; ++j) acc[i][j] = (f32x4){0.f,0.f,0.f,0.f};
    #pragma unroll
    for (int ks = 0; ks < 128; ks += 32) {
        short8 af[4], bg[4];
        #pragma unroll
        for (int j = 0; j < 4; ++j)
            bg[j] = *(const short8*)(bwc + (size_t)(wn + j*16 + lr) * CHUNK + ks + quad*8);
        #pragma unroll
        for (int i = 0; i < 4; ++i)
            af[i] = *(const short8*)(&Xs[wm + i*16 + lr][ks + quad*8]);
        #pragma unroll
        for (int i = 0; i < 4; ++i)
            #pragma unroll
            for (int j = 0; j < 4; ++j)
                acc[i][j] = __builtin_amdgcn_mfma_f32_16x16x32_bf16(af[i], bg[j], acc[i][j], 0,0,0);
    }
    #pragma unroll
    for (int i = 0; i < 4; ++i)
        #pragma unroll
        for (int j = 0; j < 4; ++j)
            #pragma unroll
            for (int r = 0; r < 4; ++r) {
                int pr = p0 + wm + i*16 + quad*4 + r;
                int n  = wn + j*16 + lr;
                dH[(size_t)chunk*(D_INNER*D_STATE) + (size_t)pr*D_STATE + n] = tbf(acc[i][j][r]);
            }
}

// ---------- sequential carry over 16 chunks/batch, fully vectorized ----------
// grid (64, BATCH): thread = (p, n-octet)
__global__ __launch_bounds__(256) void k_carry(
    const bf16* __restrict__ dH, const float* __restrict__ Pc, bf16* __restrict__ B2)
{
    int idx = blockIdx.x * 256 + threadIdx.x;   // 0..16383
    int b = blockIdx.y;
    int p = idx >> 4, ng = (idx & 15) << 3;
    uint4 v[CPB];
    float pc[CPB];
    #pragma unroll
    for (int c = 0; c < CPB; ++c)
        v[c] = *(const uint4*)(dH + (size_t)(b*CPB + c)*(D_INNER*D_STATE) + (size_t)p*D_STATE + ng);
    #pragma unroll
    for (int c = 0; c < CPB; ++c) pc[c] = Pc[b*CPB + c];
    float h[8] = {0,0,0,0,0,0,0,0};
    #pragma unroll
    for (int c = 0; c < CPB; ++c) {
        union { bf16 o[8]; uint4 u; } pk;
        #pragma unroll
        for (int k = 0; k < 8; ++k) pk.o[k] = tbf(h[k]);
        *(uint4*)(B2 + (size_t)(b*CPB + c)*(D_INNER*256) + (size_t)p*256 + 128 + ng) = pk.u;
        const bf16* vb = (const bf16*)&v[c];
        #pragma unroll
        for (int k = 0; k < 8; ++k) h[k] = pc[c]*h[k] + fbf(vb[k]);
    }
}

extern "C" void kernel_launch(void* const* d_in, const int* in_sizes, int n_in,
                              void* d_out, int out_size, void* d_ws, size_t ws_size,
                              hipStream_t stream)
{
    const float* x       = (const float*)d_in[0];
    const float* rnn     = (const float*)d_in[1];
    const float* W_in    = (const float*)d_in[2];
    const float* conv_w  = (const float*)d_in[3];
    const float* conv_b  = (const float*)d_in[4];
    const float* dt_bias = (const float*)d_in[5];
    const float* A_log   = (const float*)d_in[6];
    const float* Dp      = (const float*)d_in[7];
    const float* norm_w  = (const float*)d_in[8];
    const float* W_out   = (const float*)d_in[9];
    float* out = (float*)d_out;

    char* ws = (char*)d_ws;
    size_t off = 0;
    auto alloc = [&](size_t bytes) { void* p = ws + off; off += (bytes + 255) & ~255ULL; return p; };

    // ---- persistent ----
    bf16*  W_inbT  = (bf16*) alloc((size_t)NPROJ * D_MODEL * 2);        // 2.36M
    bf16*  W_outbT = (bf16*) alloc((size_t)D_MODEL * D_INNER * 2);      // 1.05M (norm_w folded)
    float* dts     = (float*)alloc((size_t)NROWS * 4);
    float* svec    = (float*)alloc((size_t)NROWS * 4);
    float* wvec    = (float*)alloc((size_t)NROWS * 4);
    float* esvec   = (float*)alloc((size_t)NROWS * 4);
    float* Pc      = (float*)alloc((size_t)NCHUNK * 4);
    float* ssq     = (float*)alloc((size_t)NROWS * 4);                  // RMS sumsq accum
    bf16*  zb      = (bf16*) alloc((size_t)NROWS * D_INNER * 2);        // 33.5M
    bf16*  A2      = (bf16*) alloc((size_t)NCHUNK * CHUNK * 256 * 2);   // 8.4M  [Sm | Cs]
    bf16*  B2      = (bf16*) alloc((size_t)NCHUNK * D_INNER * 256 * 2); // 67.1M [Xt | Hprev]
    bf16*  Bw      = (bf16*) alloc((size_t)NCHUNK * D_STATE * CHUNK * 2); // 4.2M
    // ---- aliased region A (50.3M): xb[0:16.8]+dH[16.8:50.3], later ybf[0:33.5] ----
    char* RA = (char*)alloc((size_t)NROWS * D_MODEL * 2 + (size_t)NROWS * D_INNER * 2);
    bf16*  xb   = (bf16*)RA;                                   // [dtcvt -> GEMM1]
    bf16*  dH   = (bf16*)(RA + (size_t)NROWS * D_MODEL * 2);   // [conv_xdh -> carry]
    bf16*  ybf  = (bf16*)RA;                                   // [Y-GEMM -> GEMM2]
    // ---- region B: xBCin [GEMM1 -> convs] ----
    bf16*  xBCin = (bf16*)alloc((size_t)NROWS * CONV_DIM * 2); // 41.9M
    // total ~200 MB

    // 0. zero the sumsq accumulator (part of the captured graph)
    hipMemsetAsync(ssq, 0, (size_t)NROWS * sizeof(float), stream);

    // 1. fused convert + dt GEMV; weight transposes (norm_w folded into W_out); cumsum prep
    k_dtcvt<<<NROWS / 4, 256, 0, stream>>>(x, W_in, dt_bias, xb, dts);
    k_transpose_cvt<<<dim3(D_MODEL/32, NPROJ/32), dim3(32, 8), 0, stream>>>(
        W_in, W_inbT, NPROJ, D_MODEL, D_IN_PROJ, nullptr);
    k_transpose_cvt<<<dim3(D_INNER/32, D_MODEL/32), dim3(32, 8), 0, stream>>>(
        W_out, W_outbT, D_MODEL, D_INNER, D_MODEL, norm_w);
    k_prep<<<NCHUNK, CHUNK, 0, stream>>>(dts, A_log, svec, wvec, esvec, Pc);

    // 2. in-projection GEMM with split output
    k_gemm_in<<<dim3(NROWS/128, NPROJ/128), 256, 0, stream>>>(xb, W_inbT, zb, xBCin, D_MODEL);

    // 3. fused conv(B,C) + G-GEMM + Sm -> A2, Bw
    k_ssd_bc<<<NCHUNK, 256, 0, stream>>>(xBCin, conv_w, conv_b, wvec, esvec,
                                         svec, dts, Dp, Bw, A2);

    // 4. fused conv(x) -> Xt(B2) + dH-GEMM
    k_conv_xdh<<<dim3(8, NCHUNK), 256, 0, stream>>>(xBCin, conv_w, conv_b, Bw, B2, dH);

    // 5. carry states -> Hprev region of B2
    k_carry<<<dim3(64, BATCH), 256, 0, stream>>>(dH, Pc, B2);

    // 6. Y = [Sm|Cs] @ [Xt|Hprev]^T  (K=256) -> gated bf16 ybf + row sumsq atomics
    k_bgemm<2><<<dim3(1, D_INNER/128, NCHUNK), 256, 0, stream>>>(
        A2, 256, (size_t)CHUNK*256,
        B2, 256, (size_t)D_INNER*256,
        ybf, D_INNER, (size_t)CHUNK*D_INNER, 256, zb, ssq);

    // 7. out-projection GEMM with RMS post-scale epilogue -> d_out
    k_bgemm<3><<<dim3(NROWS/128, D_MODEL/128, 1), 256, 0, stream>>>(
        ybf, D_INNER, 0, W_outbT, D_INNER, 0, out, D_MODEL, 0, D_INNER,
        nullptr, ssq);

    // 8. rnn_state passthrough
    hipMemcpyAsync(out + (size_t)NROWS * D_MODEL, rnn,
                   (size_t)BATCH * D_MODEL * sizeof(float),
                   hipMemcpyDeviceToDevice, stream);
}

// Round 8
// 300.180 us; speedup vs baseline: 1.2085x; 1.0697x over previous
//
#include <hip/hip_runtime.h>
#include <hip/hip_bf16.h>
#include <math.h>

#define D_MODEL 512
#define D_INNER 1024
#define D_STATE 128
#define CONV_DIM (D_INNER + 2*D_STATE)        // 1280
#define D_IN_PROJ (2*D_INNER + 2*D_STATE + 1) // 2305
#define NPROJ 2304                            // z + xBC cols (dt col via GEMV)
#define BATCH 8
#define SEQ 2048
#define NROWS (BATCH*SEQ)                     // 16384
#define CHUNK 128
#define NCHUNK (NROWS/CHUNK)                  // 128 total (16 per batch)
#define CPB (SEQ/CHUNK)                       // 16 chunks per batch
#define EPS_RMS 1e-5f

typedef __hip_bfloat16 bf16;
typedef __attribute__((ext_vector_type(8))) short short8;
typedef __attribute__((ext_vector_type(4))) float f32x4;

__device__ __forceinline__ float fbf(bf16 v) { return __bfloat162float(v); }
__device__ __forceinline__ bf16 tbf(float v) { return __float2bfloat16(v); }
__device__ __forceinline__ float fexp(float x) { return __expf(x); }          // v_exp_f32
__device__ __forceinline__ float frcp(float x) { return __builtin_amdgcn_rcpf(x); }
__device__ __forceinline__ float fsilu(float a) { return a * frcp(1.f + fexp(-a)); }

// async global->LDS, 16B per lane; LDS dest is wave-uniform base + lane*16
__device__ __forceinline__ void gl2lds16(const bf16* g, bf16* l) {
    __builtin_amdgcn_global_load_lds(
        (const __attribute__((address_space(1))) unsigned int*)g,
        (__attribute__((address_space(3))) unsigned int*)l, 16, 0, 0);
}

// ---------- prologue: both weight transposes (+norm_w fold) + rnn tail copy ----------
// 1D grid: [0,1152) = W_in^T tiles, [1152,1664) = W_out^T tiles, 1664 = rnn copy.
__global__ __launch_bounds__(256) void k_prologue(
    const float* __restrict__ W_in, const float* __restrict__ W_out,
    const float* __restrict__ norm_w, const float* __restrict__ rnn,
    bf16* __restrict__ W_inbT, bf16* __restrict__ W_outbT, float* __restrict__ outTail)
{
    int b = blockIdx.x;
    if (b == 1152 + 512) {  // rnn passthrough: 8*512 fp32
        int tid = threadIdx.x;
        #pragma unroll
        for (int i = 0; i < 4; ++i)
            *(float4*)(outTail + (tid + i * 256) * 4) =
                *(const float4*)(rnn + (tid + i * 256) * 4);
        return;
    }
    __shared__ float tile[32][33];
    const float* src; bf16* dst; const float* scale;
    int c0, r0, sstride, C;
    if (b < 1152) {           // W_in[D_MODEL][D_IN_PROJ] -> W_inbT[NPROJ][D_MODEL]
        src = W_in; dst = W_inbT; scale = nullptr;
        c0 = (b % 16) * 32; r0 = (b / 16) * 32; sstride = D_IN_PROJ; C = D_MODEL;
    } else {                  // W_out[D_INNER][D_MODEL] -> W_outbT[D_MODEL][D_INNER], *norm_w
        int bb = b - 1152;
        src = W_out; dst = W_outbT; scale = norm_w;
        c0 = (bb % 32) * 32; r0 = (bb / 32) * 32; sstride = D_MODEL; C = D_INNER;
    }
    int tx = threadIdx.x & 31, ty = threadIdx.x >> 5;
    #pragma unroll
    for (int i = 0; i < 32; i += 8) {
        float s = scale ? scale[c0 + ty + i] : 1.f;
        tile[ty + i][tx] = src[(size_t)(c0 + ty + i) * sstride + (r0 + tx)] * s;
    }
    __syncthreads();
    #pragma unroll
    for (int i = 0; i < 32; i += 8)
        dst[(size_t)(r0 + ty + i) * C + (c0 + tx)] = tbf(tile[tx][ty + i]);
}

// ---------- fused x->bf16 convert + dt GEMV + softplus + ssq zeroing ----------
__global__ __launch_bounds__(256) void k_dtcvt(
    const float* __restrict__ x, const float* __restrict__ W_in,
    const float* __restrict__ dt_bias,
    bf16* __restrict__ xb, float* __restrict__ dts, float* __restrict__ ssq)
{
    __shared__ float wcol[D_MODEL];
    int tid = threadIdx.x;
    wcol[tid]       = W_in[(size_t)tid * D_IN_PROJ + 2304];
    wcol[tid + 256] = W_in[(size_t)(tid + 256) * D_IN_PROJ + 2304];
    __syncthreads();
    int row  = blockIdx.x * 4 + (tid >> 6);
    int lane = tid & 63;
    const float* xr = x + (size_t)row * D_MODEL;
    float4 a = *(const float4*)(xr + lane * 8);
    float4 b = *(const float4*)(xr + lane * 8 + 4);
    union { bf16 o[8]; uint4 u; } pk;
    pk.o[0]=tbf(a.x); pk.o[1]=tbf(a.y); pk.o[2]=tbf(a.z); pk.o[3]=tbf(a.w);
    pk.o[4]=tbf(b.x); pk.o[5]=tbf(b.y); pk.o[6]=tbf(b.z); pk.o[7]=tbf(b.w);
    *(uint4*)(xb + (size_t)row * D_MODEL + lane * 8) = pk.u;
    const float* wc = wcol + lane * 8;
    float s = a.x*wc[0]+a.y*wc[1]+a.z*wc[2]+a.w*wc[3]
            + b.x*wc[4]+b.y*wc[5]+b.z*wc[6]+b.w*wc[7];
    #pragma unroll
    for (int off = 32; off; off >>= 1) s += __shfl_xor(s, off);
    if (lane == 0) {
        float raw = s + dt_bias[0];
        dts[row] = raw > 20.f ? raw : log1pf(fexp(raw));
        ssq[row] = 0.f;
    }
}

// ---------- batched NT GEMM, 128x128 tile, BK=64, global_load_lds + XOR swizzle ----------
// MODE 0: fp32 out.  MODE 1: bf16 out.
// MODE 2: Y-epilogue — gate with silu(zg) (zg tile staged to LDS), bf16 out, ssq atomics.
//         (requires bm==0, M==128 per batch index)
// MODE 3: fp32 out scaled by rsqrt(ssq[row]/D_INNER + eps).
template<int MODE>
__global__ __launch_bounds__(256) void k_bgemm(
    const bf16* __restrict__ A, int lda, size_t sA,
    const bf16* __restrict__ Bt, int ldb, size_t sB,
    void* __restrict__ Cv, int ldc, size_t sC, int K,
    const bf16* __restrict__ zg, float* __restrict__ ssq)
{
    constexpr int BK = 64;
    __shared__ __align__(16) bf16 SM[128 * 128];   // As = SM[0:8192], Bs = SM[8192:16384]
    bf16* As = SM;
    bf16* Bs = SM + 8192;
    const int tid = threadIdx.x, lane = tid & 63, wave = tid >> 6;
    const int wm = (wave & 1) * 64, wn = (wave >> 1) * 64;
    const int lr = lane & 15, quad = lane >> 4;
    const int rx = lr & 7;
    const size_t bm = (size_t)blockIdx.x * 128;
    const size_t bn = (size_t)blockIdx.y * 128;
    const size_t bi = blockIdx.z;
    A  += bi * sA;
    Bt += bi * sB;
    const int srow = lane >> 3;
    const int scol = (((lane & 7) ^ srow) << 3);

    f32x4 acc[4][4];
    #pragma unroll
    for (int i = 0; i < 4; ++i)
        #pragma unroll
        for (int j = 0; j < 4; ++j) acc[i][j] = (f32x4){0.f,0.f,0.f,0.f};

    for (int k0 = 0; k0 < K; k0 += BK) {
        __syncthreads();
        #pragma unroll
        for (int q = 0; q < 4; ++q) {
            int rg = wave * 32 + q * 8;
            gl2lds16(A  + (bm + rg + srow) * lda + k0 + scol, As + rg * BK);
            gl2lds16(Bt + (bn + rg + srow) * ldb + k0 + scol, Bs + rg * BK);
        }
        __syncthreads();
        #pragma unroll
        for (int ks = 0; ks < BK; ks += 32) {
            const int off = ((((ks >> 3) + quad) ^ rx) << 3);
            short8 af[4], bg[4];
            #pragma unroll
            for (int i = 0; i < 4; ++i)
                af[i] = *(const short8*)(As + (wm + i*16 + lr) * BK + off);
            #pragma unroll
            for (int j = 0; j < 4; ++j)
                bg[j] = *(const short8*)(Bs + (wn + j*16 + lr) * BK + off);
            #pragma unroll
            for (int i = 0; i < 4; ++i)
                #pragma unroll
                for (int j = 0; j < 4; ++j)
                    acc[i][j] = __builtin_amdgcn_mfma_f32_16x16x32_bf16(af[i], bg[j], acc[i][j], 0,0,0);
        }
    }
    if (MODE <= 1) {
        #pragma unroll
        for (int i = 0; i < 4; ++i)
            #pragma unroll
            for (int j = 0; j < 4; ++j)
                #pragma unroll
                for (int r = 0; r < 4; ++r) {
                    size_t row = bm + wm + i*16 + quad*4 + r;
                    size_t col = bn + wn + j*16 + lr;
                    float v = acc[i][j][r];
                    if (MODE == 0) ((float*)Cv + bi*sC)[row * ldc + col] = v;
                    else           ((bf16*)Cv + bi*sC)[row * ldc + col] = tbf(v);
                }
    } else if (MODE == 2) {
        // stage zg tile (128 rows x 128 cols, XOR-swizzled) into SM, reusing As/Bs
        const size_t tokbase = bi * CHUNK;
        const bf16* zrow = zg + tokbase * D_INNER + bn;
        __syncthreads();
        #pragma unroll
        for (int q = 0; q < 8; ++q) {
            int r0 = wave * 32 + q * 4;
            int rr = r0 + (lane >> 4);
            int gl = (lane & 15) ^ (rr & 7);
            gl2lds16(zrow + (size_t)rr * D_INNER + gl * 8, SM + r0 * 128);
        }
        __syncthreads();
        float srw[4][4];
        #pragma unroll
        for (int i = 0; i < 4; ++i)
            #pragma unroll
            for (int r = 0; r < 4; ++r) srw[i][r] = 0.f;
        #pragma unroll
        for (int i = 0; i < 4; ++i)
            #pragma unroll
            for (int j = 0; j < 4; ++j)
                #pragma unroll
                for (int r = 0; r < 4; ++r) {
                    int row = wm + i*16 + quad*4 + r;       // 0..127 (bm==0)
                    int col = wn + j*16 + lr;               // 0..127 local
                    int gph = ((col >> 3) ^ (row & 7));
                    float z = fbf(SM[row * 128 + (gph << 3) + (col & 7)]);
                    float g = acc[i][j][r] * z * frcp(1.f + fexp(-z));
                    ((bf16*)Cv + bi*sC)[(size_t)row * ldc + bn + col] = tbf(g);
                    srw[i][r] += g * g;
                }
        #pragma unroll
        for (int i = 0; i < 4; ++i)
            #pragma unroll
            for (int r = 0; r < 4; ++r) {
                float s = srw[i][r];
                s += __shfl_xor(s, 1);
                s += __shfl_xor(s, 2);
                s += __shfl_xor(s, 4);
                s += __shfl_xor(s, 8);
                if (lr == 0)
                    atomicAdd(ssq + tokbase + wm + i*16 + quad*4 + r, s);
            }
    } else {  // MODE 3
        #pragma unroll
        for (int i = 0; i < 4; ++i)
            #pragma unroll
            for (int r = 0; r < 4; ++r) {
                size_t row = bm + wm + i*16 + quad*4 + r;
                float sc = rsqrtf(ssq[row] * (1.f / D_INNER) + EPS_RMS);
                #pragma unroll
                for (int j = 0; j < 4; ++j) {
                    size_t col = bn + wn + j*16 + lr;
                    ((float*)Cv + bi*sC)[row * ldc + col] = acc[i][j][r] * sc;
                }
            }
    }
}

// ---------- GEMM1 with split output: cols<1024 -> zb, else xBCin ----------
__global__ __launch_bounds__(256) void k_gemm_in(
    const bf16* __restrict__ A, const bf16* __restrict__ Bt,
    bf16* __restrict__ zb, bf16* __restrict__ xBCin, int K)
{
    constexpr int BK = 64;
    __shared__ __align__(16) bf16 As[128][BK];
    __shared__ __align__(16) bf16 Bs[128][BK];
    const int tid = threadIdx.x, lane = tid & 63, wave = tid >> 6;
    const int wm = (wave & 1) * 64, wn = (wave >> 1) * 64;
    const int lr = lane & 15, quad = lane >> 4;
    const int rx = lr & 7;
    const size_t bm = (size_t)blockIdx.x * 128;
    const int bn = blockIdx.y * 128;
    const int srow = lane >> 3;
    const int scol = (((lane & 7) ^ srow) << 3);

    f32x4 acc[4][4];
    #pragma unroll
    for (int i = 0; i < 4; ++i)
        #pragma unroll
        for (int j = 0; j < 4; ++j) acc[i][j] = (f32x4){0.f,0.f,0.f,0.f};

    for (int k0 = 0; k0 < K; k0 += BK) {
        __syncthreads();
        #pragma unroll
        for (int q = 0; q < 4; ++q) {
            int rg = wave * 32 + q * 8;
            gl2lds16(A  + (bm + rg + srow) * K + k0 + scol, &As[rg][0]);
            gl2lds16(Bt + ((size_t)bn + rg + srow) * K + k0 + scol, &Bs[rg][0]);
        }
        __syncthreads();
        #pragma unroll
        for (int ks = 0; ks < BK; ks += 32) {
            const int off = ((((ks >> 3) + quad) ^ rx) << 3);
            short8 af[4], bg[4];
            #pragma unroll
            for (int i = 0; i < 4; ++i)
                af[i] = *(const short8*)(&As[wm + i*16 + lr][off]);
            #pragma unroll
            for (int j = 0; j < 4; ++j)
                bg[j] = *(const short8*)(&Bs[wn + j*16 + lr][off]);
            #pragma unroll
            for (int i = 0; i < 4; ++i)
                #pragma unroll
                for (int j = 0; j < 4; ++j)
                    acc[i][j] = __builtin_amdgcn_mfma_f32_16x16x32_bf16(af[i], bg[j], acc[i][j], 0,0,0);
        }
    }
    #pragma unroll
    for (int i = 0; i < 4; ++i)
        #pragma unroll
        for (int j = 0; j < 4; ++j)
            #pragma unroll
            for (int r = 0; r < 4; ++r) {
                size_t row = bm + wm + i*16 + quad*4 + r;
                int col = bn + wn + j*16 + lr;
                float v = acc[i][j][r];
                if (col < D_INNER) zb[row * D_INNER + col] = tbf(v);
                else xBCin[row * CONV_DIM + (col - D_INNER)] = tbf(v);
            }
}

// ---------- per-chunk cumsum of a_t = A*dt, decay factors ----------
__global__ void k_prep(const float* __restrict__ dts, const float* __restrict__ A_log,
                       float* __restrict__ svec, float* __restrict__ wvec,
                       float* __restrict__ esvec, float* __restrict__ Pc)
{
    int chunk = blockIdx.x, t = threadIdx.x;  // 128 threads
    int row = chunk * CHUNK + t;
    float A = -fexp(A_log[0]);
    __shared__ float sh[CHUNK];
    sh[t] = A * dts[row];
    __syncthreads();
    for (int off = 1; off < CHUNK; off <<= 1) {
        float v = (t >= off) ? sh[t - off] : 0.f;
        __syncthreads();
        sh[t] += v;
        __syncthreads();
    }
    float s = sh[t], sL = sh[CHUNK - 1];
    svec[row]  = s;
    wvec[row]  = fexp(sL - s) * dts[row];
    esvec[row] = fexp(s);
    if (t == CHUNK - 1) Pc[chunk] = fexp(sL);
}

// ---------- fused conv(B,C) + G = C@B^T + Sm epilogue + Bw/Cs builds ----------
// grid NCHUNK, 256 threads.
__global__ __launch_bounds__(256) void k_ssd_bc(
    const bf16* __restrict__ xBCin, const float* __restrict__ conv_w,
    const float* __restrict__ conv_b, const float* __restrict__ wvec,
    const float* __restrict__ esvec, const float* __restrict__ svec,
    const float* __restrict__ dts, const float* __restrict__ Dp,
    bf16* __restrict__ Bw, bf16* __restrict__ A2)
{
    __shared__ __align__(16) bf16 Ls[131][128];
    __shared__ __align__(16) bf16 Bts[128][136];
    __shared__ __align__(16) bf16 Cts[128][136];
    __shared__ float sv_s[128], dt_s[128], wv_s[128], es_s[128];
    const int chunk = blockIdx.x;
    const int tid = threadIdx.x;
    const bool first = (chunk % CPB) == 0;
    const size_t rowbase = (size_t)chunk * CHUNK;
    if (tid < 128) {
        sv_s[tid] = svec[rowbase + tid];
        dt_s[tid] = dts[rowbase + tid];
        wv_s[tid] = wvec[rowbase + tid];
        es_s[tid] = esvec[rowbase + tid];
    }
    const int ch  = tid & 127;
    const int seg = tid >> 7;   // t-half

    #pragma unroll
    for (int phase = 0; phase < 2; ++phase) {
        const int coff = D_INNER + phase * 128;   // B then C channel base
        __syncthreads();
        for (int i = tid; i < 131 * 16; i += 256) {
            int r = i >> 4, cg = (i & 15) << 3;
            uint4 v = (uint4){0,0,0,0};
            if (!(first && r < 3))
                v = *(const uint4*)(xBCin + (rowbase + r - 3) * CONV_DIM + coff + cg);
            *(uint4*)(&Ls[r][cg]) = v;
        }
        __syncthreads();
        float4 w = *(const float4*)(conv_w + (coff + ch) * 4);
        float bias = conv_b[coff + ch];
        float xv[11];
        #pragma unroll
        for (int i = 0; i < 3; ++i) xv[i + 8] = fbf(Ls[seg * 64 + i][ch]);
        for (int v = 0; v < 8; ++v) {
            int t0 = seg * 64 + v * 8;
            xv[0]=xv[8]; xv[1]=xv[9]; xv[2]=xv[10];
            #pragma unroll
            for (int i = 3; i < 11; ++i) xv[i] = fbf(Ls[t0 + i][ch]);
            float o[8];
            #pragma unroll
            for (int j = 0; j < 8; ++j) {
                float a = bias + w.x*xv[j] + w.y*xv[j+1] + w.z*xv[j+2] + w.w*xv[j+3];
                o[j] = fsilu(a);
            }
            if (phase == 0) {
                union { bf16 ob[8]; uint4 u; } pk;
                #pragma unroll
                for (int j = 0; j < 8; ++j) {
                    Bts[t0 + j][ch] = tbf(o[j]);
                    pk.ob[j] = tbf(o[j] * wv_s[t0 + j]);
                }
                *(uint4*)(Bw + (size_t)chunk*(D_STATE*CHUNK) + (size_t)ch*CHUNK + t0) = pk.u;
            } else {
                #pragma unroll
                for (int j = 0; j < 8; ++j) {
                    Cts[t0 + j][ch] = tbf(o[j]);
                    A2[(size_t)chunk*(CHUNK*256) + (size_t)(t0+j)*256 + 128 + ch] =
                        tbf(o[j] * es_s[t0 + j]);
                }
            }
        }
    }
    __syncthreads();
    // G = C @ B^T from LDS (K=128), Sm epilogue -> A2[:, 0:128]
    const int lane = tid & 63, wave = tid >> 6;
    const int wm = (wave & 1) * 64, wn = (wave >> 1) * 64;
    const int lr = lane & 15, quad = lane >> 4;
    f32x4 acc[4][4];
    #pragma unroll
    for (int i = 0; i < 4; ++i)
        #pragma unroll
        for (int j = 0; j < 4; ++j) acc[i][j] = (f32x4){0.f,0.f,0.f,0.f};
    #pragma unroll
    for (int ks = 0; ks < 128; ks += 32) {
        short8 af[4], bg[4];
        #pragma unroll
        for (int i = 0; i < 4; ++i)
            af[i] = *(const short8*)(&Cts[wm + i*16 + lr][ks + quad*8]);
        #pragma unroll
        for (int j = 0; j < 4; ++j)
            bg[j] = *(const short8*)(&Bts[wn + j*16 + lr][ks + quad*8]);
        #pragma unroll
        for (int i = 0; i < 4; ++i)
            #pragma unroll
            for (int j = 0; j < 4; ++j)
                acc[i][j] = __builtin_amdgcn_mfma_f32_16x16x32_bf16(af[i], bg[j], acc[i][j], 0,0,0);
    }
    const float D0 = Dp[0];
    #pragma unroll
    for (int i = 0; i < 4; ++i)
        #pragma unroll
        for (int j = 0; j < 4; ++j)
            #pragma unroll
            for (int r = 0; r < 4; ++r) {
                int t = wm + i*16 + quad*4 + r;
                int u = wn + j*16 + lr;
                float o = 0.f;
                if (u <= t) {
                    o = acc[i][j][r] * fexp(sv_s[t] - sv_s[u]) * dt_s[u];
                    if (u == t) o += D0;
                }
                A2[(size_t)chunk*(CHUNK*256) + (size_t)t*256 + u] = tbf(o);
            }
}

// ---------- fused conv(x) -> Xt (B2 + swizzled LDS) + dH = Xt @ Bw^T ----------
// grid (8, NCHUNK), 256 threads. LDS ~65.5 KB -> 2 blocks/CU.
__global__ __launch_bounds__(256) void k_conv_xdh(
    const bf16* __restrict__ xBCin, const float* __restrict__ conv_w,
    const float* __restrict__ conv_b, const bf16* __restrict__ Bw,
    bf16* __restrict__ B2, bf16* __restrict__ dH)
{
    __shared__ __align__(16) bf16 Ls[131][128];
    __shared__ __align__(16) bf16 XsF[128 * 128];  // [p][t], t-groups XOR-swizzled by p&7
    const int chunk = blockIdx.y;
    const int p0 = blockIdx.x * 128;
    const int tid = threadIdx.x;
    const bool first = (chunk % CPB) == 0;
    const size_t rowbase = (size_t)chunk * CHUNK;
    for (int i = tid; i < 131 * 16; i += 256) {
        int r = i >> 4, cg = (i & 15) << 3;
        uint4 v = (uint4){0,0,0,0};
        if (!(first && r < 3))
            v = *(const uint4*)(xBCin + (rowbase + r - 3) * CONV_DIM + p0 + cg);
        *(uint4*)(&Ls[r][cg]) = v;
    }
    __syncthreads();
    const int p = tid & 127;
    const int half = tid >> 7;
    const int ch = p0 + p;
    float4 w = *(const float4*)(conv_w + ch * 4);
    float bias = conv_b[ch];
    bf16* outrow = B2 + (size_t)chunk * (D_INNER * 256) + (size_t)ch * 256;
    float xv[11];
    #pragma unroll
    for (int i = 0; i < 3; ++i) xv[i + 8] = fbf(Ls[half * 64 + i][p]);
    for (int v = 0; v < 8; ++v) {
        int t0 = half * 64 + v * 8;
        xv[0]=xv[8]; xv[1]=xv[9]; xv[2]=xv[10];
        #pragma unroll
        for (int i = 3; i < 11; ++i) xv[i] = fbf(Ls[t0 + i][p]);
        union { bf16 o[8]; uint4 u; } pk;
        #pragma unroll
        for (int j = 0; j < 8; ++j) {
            float a = bias + w.x*xv[j] + w.y*xv[j+1] + w.z*xv[j+2] + w.w*xv[j+3];
            pk.o[j] = tbf(fsilu(a));
        }
        *(uint4*)(outrow + t0) = pk.u;
        *(uint4*)(&XsF[p * 128 + ((((t0 >> 3) ^ (p & 7))) << 3)]) = pk.u;
    }
    __syncthreads();
    // dH[p][n] = sum_t Xs[p][t] * Bw[n][t]  (K=128; B-frags straight from global)
    const int lane = tid & 63, wave = tid >> 6;
    const int wm = (wave & 1) * 64, wn = (wave >> 1) * 64;
    const int lr = lane & 15, quad = lane >> 4;
    const bf16* bwc = Bw + (size_t)chunk * (D_STATE * CHUNK);
    f32x4 acc[4][4];
    #pragma unroll
    for (int i = 0; i < 4; ++i)
        #pragma unroll
        for (int j = 0; j < 4; ++j) acc[i][j] = (f32x4){0.f,0.f,0.f,0.f};
    #pragma unroll
    for (int ks = 0; ks < 128; ks += 32) {
        short8 af[4], bg[4];
        #pragma unroll
        for (int j = 0; j < 4; ++j)
            bg[j] = *(const short8*)(bwc + (size_t)(wn + j*16 + lr) * CHUNK + ks + quad*8);
        #pragma unroll
        for (int i = 0; i < 4; ++i)
            af[i] = *(const short8*)(&XsF[(wm + i*16 + lr) * 128 +
                                          (((((ks >> 3) + quad) ^ (lr & 7))) << 3)]);
        #pragma unroll
        for (int i = 0; i < 4; ++i)
            #pragma unroll
            for (int j = 0; j < 4; ++j)
                acc[i][j] = __builtin_amdgcn_mfma_f32_16x16x32_bf16(af[i], bg[j], acc[i][j], 0,0,0);
    }
    #pragma unroll
    for (int i = 0; i < 4; ++i)
        #pragma unroll
        for (int j = 0; j < 4; ++j)
            #pragma unroll
            for (int r = 0; r < 4; ++r) {
                int pr = p0 + wm + i*16 + quad*4 + r;
                int n  = wn + j*16 + lr;
                dH[(size_t)chunk*(D_INNER*D_STATE) + (size_t)pr*D_STATE + n] = tbf(acc[i][j][r]);
            }
}

// ---------- sequential carry over 16 chunks/batch, fully vectorized ----------
__global__ __launch_bounds__(256) void k_carry(
    const bf16* __restrict__ dH, const float* __restrict__ Pc, bf16* __restrict__ B2)
{
    int idx = blockIdx.x * 256 + threadIdx.x;   // 0..16383
    int b = blockIdx.y;
    int p = idx >> 4, ng = (idx & 15) << 3;
    uint4 v[CPB];
    float pc[CPB];
    #pragma unroll
    for (int c = 0; c < CPB; ++c)
        v[c] = *(const uint4*)(dH + (size_t)(b*CPB + c)*(D_INNER*D_STATE) + (size_t)p*D_STATE + ng);
    #pragma unroll
    for (int c = 0; c < CPB; ++c) pc[c] = Pc[b*CPB + c];
    float h[8] = {0,0,0,0,0,0,0,0};
    #pragma unroll
    for (int c = 0; c < CPB; ++c) {
        union { bf16 o[8]; uint4 u; } pk;
        #pragma unroll
        for (int k = 0; k < 8; ++k) pk.o[k] = tbf(h[k]);
        *(uint4*)(B2 + (size_t)(b*CPB + c)*(D_INNER*256) + (size_t)p*256 + 128 + ng) = pk.u;
        const bf16* vb = (const bf16*)&v[c];
        #pragma unroll
        for (int k = 0; k < 8; ++k) h[k] = pc[c]*h[k] + fbf(vb[k]);
    }
}

extern "C" void kernel_launch(void* const* d_in, const int* in_sizes, int n_in,
                              void* d_out, int out_size, void* d_ws, size_t ws_size,
                              hipStream_t stream)
{
    const float* x       = (const float*)d_in[0];
    const float* rnn     = (const float*)d_in[1];
    const float* W_in    = (const float*)d_in[2];
    const float* conv_w  = (const float*)d_in[3];
    const float* conv_b  = (const float*)d_in[4];
    const float* dt_bias = (const float*)d_in[5];
    const float* A_log   = (const float*)d_in[6];
    const float* Dp      = (const float*)d_in[7];
    const float* norm_w  = (const float*)d_in[8];
    const float* W_out   = (const float*)d_in[9];
    float* out = (float*)d_out;

    char* ws = (char*)d_ws;
    size_t off = 0;
    auto alloc = [&](size_t bytes) { void* p = ws + off; off += (bytes + 255) & ~255ULL; return p; };

    // ---- persistent ----
    bf16*  W_inbT  = (bf16*) alloc((size_t)NPROJ * D_MODEL * 2);        // 2.36M
    bf16*  W_outbT = (bf16*) alloc((size_t)D_MODEL * D_INNER * 2);      // 1.05M (norm_w folded)
    float* dts     = (float*)alloc((size_t)NROWS * 4);
    float* svec    = (float*)alloc((size_t)NROWS * 4);
    float* wvec    = (float*)alloc((size_t)NROWS * 4);
    float* esvec   = (float*)alloc((size_t)NROWS * 4);
    float* Pc      = (float*)alloc((size_t)NCHUNK * 4);
    float* ssq     = (float*)alloc((size_t)NROWS * 4);                  // RMS sumsq accum
    bf16*  zb      = (bf16*) alloc((size_t)NROWS * D_INNER * 2);        // 33.5M
    bf16*  A2      = (bf16*) alloc((size_t)NCHUNK * CHUNK * 256 * 2);   // 8.4M  [Sm | Cs]
    bf16*  B2      = (bf16*) alloc((size_t)NCHUNK * D_INNER * 256 * 2); // 67.1M [Xt | Hprev]
    bf16*  Bw      = (bf16*) alloc((size_t)NCHUNK * D_STATE * CHUNK * 2); // 4.2M
    // ---- aliased region A (50.3M): xb[0:16.8]+dH[16.8:50.3], later ybf[0:33.5] ----
    char* RA = (char*)alloc((size_t)NROWS * D_MODEL * 2 + (size_t)NROWS * D_INNER * 2);
    bf16*  xb   = (bf16*)RA;                                   // [dtcvt -> GEMM1]
    bf16*  dH   = (bf16*)(RA + (size_t)NROWS * D_MODEL * 2);   // [conv_xdh -> carry]
    bf16*  ybf  = (bf16*)RA;                                   // [Y-GEMM -> GEMM2]
    // ---- region B: xBCin [GEMM1 -> convs] ----
    bf16*  xBCin = (bf16*)alloc((size_t)NROWS * CONV_DIM * 2); // 41.9M
    // total ~200 MB

    // 1. fused convert + dt GEMV + ssq zeroing; prologue (transposes + rnn copy); prep
    k_dtcvt<<<NROWS / 4, 256, 0, stream>>>(x, W_in, dt_bias, xb, dts, ssq);
    k_prologue<<<1152 + 512 + 1, 256, 0, stream>>>(
        W_in, W_out, norm_w, rnn, W_inbT, W_outbT, out + (size_t)NROWS * D_MODEL);
    k_prep<<<NCHUNK, CHUNK, 0, stream>>>(dts, A_log, svec, wvec, esvec, Pc);

    // 2. in-projection GEMM with split output
    k_gemm_in<<<dim3(NROWS/128, NPROJ/128), 256, 0, stream>>>(xb, W_inbT, zb, xBCin, D_MODEL);

    // 3. fused conv(B,C) + G-GEMM + Sm -> A2, Bw
    k_ssd_bc<<<NCHUNK, 256, 0, stream>>>(xBCin, conv_w, conv_b, wvec, esvec,
                                         svec, dts, Dp, Bw, A2);

    // 4. fused conv(x) -> Xt(B2) + dH-GEMM
    k_conv_xdh<<<dim3(8, NCHUNK), 256, 0, stream>>>(xBCin, conv_w, conv_b, Bw, B2, dH);

    // 5. carry states -> Hprev region of B2
    k_carry<<<dim3(64, BATCH), 256, 0, stream>>>(dH, Pc, B2);

    // 6. Y = [Sm|Cs] @ [Xt|Hprev]^T (K=256) -> gated bf16 ybf + row sumsq atomics
    k_bgemm<2><<<dim3(1, D_INNER/128, NCHUNK), 256, 0, stream>>>(
        A2, 256, (size_t)CHUNK*256,
        B2, 256, (size_t)D_INNER*256,
        ybf, D_INNER, (size_t)CHUNK*D_INNER, 256, zb, ssq);

    // 7. out-projection GEMM with RMS post-scale epilogue -> d_out
    k_bgemm<3><<<dim3(NROWS/128, D_MODEL/128, 1), 256, 0, stream>>>(
        ybf, D_INNER, 0, W_outbT, D_INNER, 0, out, D_MODEL, 0, D_INNER,
        nullptr, ssq);
}